// Round 12
// baseline (2113.732 us; speedup 1.0000x reference)
//
#include <hip/hip_runtime.h>

#define N_NODESC 50000
#define N_PAD 50176          // 392 * 128
#define N_EDGESC 800000
#define N_GRAPHSC 128
#define EMBEDC 256
#define MTILES 392
#define SLAB ((long)N_PAD * 32)   // halves per 32-col slice slab

typedef __attribute__((ext_vector_type(8))) _Float16 hf8;
typedef __attribute__((ext_vector_type(4))) float fx4;
typedef __attribute__((ext_vector_type(4))) unsigned int ux4;

__device__ __forceinline__ float h2f(unsigned short u) {
  _Float16 h = *(_Float16*)&u;
  return (float)h;
}
__device__ __forceinline__ unsigned short f2h(float f) {
  _Float16 h = (_Float16)f;
  return *(unsigned short*)&h;
}
__device__ __forceinline__ unsigned int packh2(float lo, float hi) {
  return (unsigned int)f2h(lo) | ((unsigned int)f2h(hi) << 16);
}

// ------------------------------------------- atom encoder (slice-major h16)
__global__ __launch_bounds__(256) void atom_encode_k(
    const int* __restrict__ nfeat, const float* __restrict__ atom_emb,
    unsigned short* __restrict__ h16)
{
  int w = threadIdx.x >> 6, lane = threadIdx.x & 63;
  int n = blockIdx.x * 4 + w;
  if (n >= N_NODESC) return;
  const int* nf = nfeat + n * 9;
  float ax = 0.f, ay = 0.f, az = 0.f, aw = 0.f;
#pragma unroll
  for (int c = 0; c < 9; ++c) {
    int idx = nf[c];
    const float4* row = (const float4*)(atom_emb + (c * 128 + idx) * EMBEDC);
    float4 v = row[lane];
    ax += v.x; ay += v.y; az += v.z; aw += v.w;
  }
  ushort4 o;
  o.x = f2h(ax); o.y = f2h(ay); o.z = f2h(az); o.w = f2h(aw);
  int col = lane * 4;
  *(ushort4*)(h16 + (long)(col >> 5) * SLAB + (long)n * 32 + (col & 31)) = o;
}

// ---------------------------------------------------------------- degree count
__global__ __launch_bounds__(256) void deg_k(
    const int* __restrict__ dst, int* __restrict__ degs)
{
  int e = blockIdx.x * 256 + threadIdx.x;
  if (e >= N_EDGESC) return;
  atomicAdd(&degs[dst[e]], 1);
}

// ---------------------------------------------------------------- exclusive scan
__global__ __launch_bounds__(1024) void scan_k(
    const int* __restrict__ deg, int* __restrict__ row_start, int n)
{
  __shared__ int buf[1024];
  __shared__ int carry;
  int t = threadIdx.x;
  if (t == 0) carry = 0;
  __syncthreads();
  for (int base = 0; base < n; base += 8192) {
    int loc[8];
    int s = 0;
    int idx0 = base + t * 8;
#pragma unroll
    for (int i = 0; i < 8; ++i) {
      int v = (idx0 + i < n) ? deg[idx0 + i] : 0;
      loc[i] = v; s += v;
    }
    buf[t] = s;
    __syncthreads();
    for (int off = 1; off < 1024; off <<= 1) {
      int add = (t >= off) ? buf[t - off] : 0;
      __syncthreads();
      buf[t] += add;
      __syncthreads();
    }
    int excl = buf[t] - s;
    int run = carry + excl;
#pragma unroll
    for (int i = 0; i < 8; ++i) {
      if (idx0 + i < n) row_start[idx0 + i] = run;
      run += loc[i];
    }
    __syncthreads();
    if (t == 1023) carry += buf[1023];
    __syncthreads();
  }
  if (t == 0) row_start[n] = carry;
}

// ---------------------------------------------------------------- CSR scatter
__global__ __launch_bounds__(256) void scatter_k(
    const int* __restrict__ src, const int* __restrict__ dst,
    const int* __restrict__ row_start, int* __restrict__ fill,
    int* __restrict__ csrc, int* __restrict__ ceid)
{
  int e = blockIdx.x * 256 + threadIdx.x;
  if (e >= N_EDGESC) return;
  int d = dst[e];
  int pos = row_start[d] + atomicAdd(&fill[d], 1);
  csrc[pos] = src[e];
  ceid[pos] = e;
}

// ------------------------------- per-node edge-feature histogram (uchar out)
__global__ __launch_bounds__(256) void cnt_k(
    const int* __restrict__ ceid, const int* __restrict__ row_start,
    const int* __restrict__ efeat, unsigned char* __restrict__ cntc)
{
  __shared__ int lc[256 * 25];
  int t = threadIdx.x;
  int n = blockIdx.x * 256 + t;
  int base = t * 25;
#pragma unroll
  for (int j = 0; j < 24; ++j) lc[base + j] = 0;
  if (n >= N_NODESC) return;
  int s0 = row_start[n], s1 = row_start[n + 1];
  for (int e = s0; e < s1; ++e) {
    int eid = ceid[e];
    int v0 = efeat[eid * 3 + 0];
    int v1 = efeat[eid * 3 + 1];
    int v2 = efeat[eid * 3 + 2];
    lc[base + v0]++;
    lc[base + 8 + v1]++;
    lc[base + 16 + v2]++;
  }
#pragma unroll
  for (int j = 0; j < 24; ++j) cntc[n * 24 + j] = (unsigned char)lc[base + j];
}

// ------------------------------------------------ W transpose + fp16 convert
__global__ __launch_bounds__(256) void wprep_k(
    const float* __restrict__ W, unsigned short* __restrict__ Wt)
{
  int tid = blockIdx.x * 256 + threadIdx.x;     // 5*65536
  int l = tid >> 16, r = tid & 65535;
  int n = r >> 8, k = r & 255;
  float w = W[(long)l * 65536 + k * 256 + n];
  Wt[tid] = f2h(w);                             // tid == l*65536 + n*256 + k
}

// ---------------------------------------------------------------- aggregation
// XCD-sliced: block's slice = blockIdx%8 (round-robin -> same XCD); each XCD's
// L2 only holds its 3.2MB column slab. Wave = 1 node; 16 edges/load-instr
// (4 lanes x 16B cover the 64B slice of each edge row). Index/cnt streams are
// nontemporal so they don't evict the slab; X16 output is nontemporal.
template<int FUSE_BN>
__device__ __forceinline__ void bnacc(const uint4 u, float* a,
                                      const hf8 scv, const hf8 shv)
{
  union { uint4 u4; hf8 h8; } cv;
  cv.u4 = u;
  hf8 y = cv.h8;
  if (FUSE_BN) {
    y = y * scv + shv;                       // v_pk_fma_f16 x4
    y = __builtin_elementwise_max(y, (hf8)0);// v_pk_max_f16 x4
  }
#pragma unroll
  for (int k = 0; k < 8; ++k) a[k] += (float)y[k];
}

template<int FUSE_BN>
__global__ __launch_bounds__(256) void aggregate_t(
    const unsigned short* __restrict__ tab_base, const float* __restrict__ emb_l,
    const int* __restrict__ csrc, const int* __restrict__ row_start,
    const unsigned char* __restrict__ cntc, const float* __restrict__ scale,
    const float* __restrict__ shiftv, unsigned short* __restrict__ X16)
{
  __shared__ unsigned short semb[24 * 32];       // this slice of edge emb, fp16
  int bid = blockIdx.x;
  int s = bid & 7;                               // slice == XCD (heuristic)
  int grp = bid >> 3;
  for (int i = threadIdx.x; i < 24 * 16; i += 256) {
    int j = i >> 4, cc = (i & 15) * 2;
    float2 f = *(const float2*)&emb_l[j * 256 + s * 32 + cc];
    *(unsigned int*)&semb[j * 32 + cc] = packh2(f.x, f.y);
  }
  __syncthreads();
  int w = threadIdx.x >> 6, lane = threadIdx.x & 63;
  int n = grp * 4 + w;                           // 12500*4 == 50000 exactly
  int g = lane >> 2, q = lane & 3;               // edge-group, 16B chunk
  const unsigned short* tab = tab_base + (long)s * SLAB;
  hf8 scv = (hf8)0, shv = (hf8)0;
  int cbase = s * 32 + q * 8;
  if (FUSE_BN) {
#pragma unroll
    for (int k = 0; k < 8; ++k) {
      scv[k] = (_Float16)scale[cbase + k];
      shv[k] = (_Float16)shiftv[cbase + k];
    }
  }
  float a[8] = {0.f, 0.f, 0.f, 0.f, 0.f, 0.f, 0.f, 0.f};
  int s0 = row_start[n], s1 = row_start[n + 1];
  if (g == 0) {                                  // self row (once, pre-reduce)
    uint4 u = *(const uint4*)(tab + (long)n * 32 + q * 8);
    bnacc<FUSE_BN>(u, a, scv, shv);
  }
  for (int eb = s0; eb < s1; eb += 16) {
    int e = eb + g;
    if (e < s1) {
      int idx = __builtin_nontemporal_load(csrc + e);
      uint4 u = *(const uint4*)(tab + (long)idx * 32 + q * 8);
      bnacc<FUSE_BN>(u, a, scv, shv);
    }
  }
  // reduce over the 16 edge-groups (lane bits 2..5)
#pragma unroll
  for (int k = 0; k < 8; ++k) {
    a[k] += __shfl_xor(a[k], 4);
    a[k] += __shfl_xor(a[k], 8);
    a[k] += __shfl_xor(a[k], 16);
    a[k] += __shfl_xor(a[k], 32);
  }
  // edge-embedding histogram term (post-reduce; identical across groups)
  {
    const unsigned int* cw = (const unsigned int*)(cntc + n * 24);
    unsigned int cu[6];
#pragma unroll
    for (int i = 0; i < 6; ++i) cu[i] = __builtin_nontemporal_load(cw + i);
#pragma unroll
    for (int j = 0; j < 24; ++j) {
      int cj = (cu[j >> 2] >> ((j & 3) * 8)) & 255;
      if (cj) {
        float fc = (float)cj;
        uint4 up = *(const uint4*)&semb[j * 32 + q * 8];
        unsigned int wsv[4] = {up.x, up.y, up.z, up.w};
#pragma unroll
        for (int t2 = 0; t2 < 4; ++t2) {
          a[2 * t2]     += fc * h2f((unsigned short)(wsv[t2] & 0xFFFF));
          a[2 * t2 + 1] += fc * h2f((unsigned short)(wsv[t2] >> 16));
        }
      }
    }
  }
  if (lane < 4) {                                // g==0 writes the 64B slice
    float inv = 1.0f / (float)(s1 - s0 + 1);
    ux4 o;
    o.x = packh2(a[0] * inv, a[1] * inv);
    o.y = packh2(a[2] * inv, a[3] * inv);
    o.z = packh2(a[4] * inv, a[5] * inv);
    o.w = packh2(a[6] * inv, a[7] * inv);
    __builtin_nontemporal_store(o,
        (ux4*)(X16 + (long)s * SLAB + (long)n * 32 + q * 8));
  }
}

// ---------------------------------------------------------------- MFMA GEMM fp16
// Y16 = fp16(X @ W + b); slice-major X/Y; per-block BN partials (no atomics)
__global__ __launch_bounds__(256) void gemm_k(
    const unsigned short* __restrict__ X16, const unsigned short* __restrict__ Bt,
    const float* __restrict__ bl, unsigned short* __restrict__ Y16,
    float* __restrict__ Pp)
{
  __shared__ unsigned short As[128 * 72];
  __shared__ unsigned short Bs[128 * 72];
  __shared__ float red_s[256];
  __shared__ float red_q[256];

  int t = threadIdx.x;
  int bm = blockIdx.x, bn = blockIdx.y;
  int row0 = bm * 128, nc0 = bn * 128;
  int w = t >> 6, l = t & 63;
  int wr = w >> 1, wc = w & 1;
  int lr = l & 15, lk = l >> 4;

  fx4 acc[4][4];
#pragma unroll
  for (int i = 0; i < 4; ++i)
#pragma unroll
    for (int j = 0; j < 4; ++j) acc[i][j] = (fx4){0.f, 0.f, 0.f, 0.f};

  for (int kc = 0; kc < 256; kc += 64) {
    __syncthreads();
#pragma unroll
    for (int q = 0; q < 2; ++q) {
      int id = q * 256 + t;
      int r = id >> 2, c16 = (id & 3) << 4;
      int ktot = kc + c16;
      long gA = (long)(ktot >> 5) * SLAB + (long)(row0 + r) * 32 + (ktot & 31);
      long gB = (long)(nc0 + r) * 256 + ktot;
      *(uint4*)&As[r * 72 + c16] = *(const uint4*)(X16 + gA);
      *(uint4*)&As[r * 72 + c16 + 8] = *(const uint4*)(X16 + gA + 8);
      *(uint4*)&Bs[r * 72 + c16] = *(const uint4*)(Bt + gB);
      *(uint4*)&Bs[r * 72 + c16 + 8] = *(const uint4*)(Bt + gB + 8);
    }
    __syncthreads();
#pragma unroll
    for (int ks = 0; ks < 2; ++ks) {
      int ko = ks * 32 + lk * 8;
      hf8 af[4], bf[4];
#pragma unroll
      for (int f = 0; f < 4; ++f) {
        af[f] = *(const hf8*)&As[(wr * 64 + f * 16 + lr) * 72 + ko];
        bf[f] = *(const hf8*)&Bs[(wc * 64 + f * 16 + lr) * 72 + ko];
      }
#pragma unroll
      for (int fm = 0; fm < 4; ++fm)
#pragma unroll
        for (int fn = 0; fn < 4; ++fn)
          acc[fm][fn] = __builtin_amdgcn_mfma_f32_16x16x32_f16(
              af[fm], bf[fn], acc[fm][fn], 0, 0, 0);
    }
  }

  float bcol[4];
#pragma unroll
  for (int fn = 0; fn < 4; ++fn) bcol[fn] = bl[nc0 + wc * 64 + fn * 16 + lr];
  float sp[4] = {0.f, 0.f, 0.f, 0.f}, qp[4] = {0.f, 0.f, 0.f, 0.f};
#pragma unroll
  for (int fm = 0; fm < 4; ++fm)
#pragma unroll
    for (int fn = 0; fn < 4; ++fn) {
      int cl = wc * 64 + fn * 16 + lr;
      int col = nc0 + cl;
      long ybase = (long)(col >> 5) * SLAB + (col & 31);
#pragma unroll
      for (int j = 0; j < 4; ++j) {
        int rl = wr * 64 + fm * 16 + lk * 4 + j;
        float v = acc[fm][fn][j] + bcol[fn];
        Y16[ybase + (long)(row0 + rl) * 32] = f2h(v);
        sp[fn] += v; qp[fn] += v * v;
      }
    }
#pragma unroll
  for (int fn = 0; fn < 4; ++fn) {
    sp[fn] += __shfl_xor(sp[fn], 16);
    sp[fn] += __shfl_xor(sp[fn], 32);
    qp[fn] += __shfl_xor(qp[fn], 16);
    qp[fn] += __shfl_xor(qp[fn], 32);
  }
  if (lk == 0) {
#pragma unroll
    for (int fn = 0; fn < 4; ++fn) {
      red_s[w * 64 + fn * 16 + lr] = sp[fn];
      red_q[w * 64 + fn * 16 + lr] = qp[fn];
    }
  }
  __syncthreads();
  if (t < 128) {
    float s = red_s[t] + red_s[128 + t];
    float q = red_q[t] + red_q[128 + t];
    float* p = Pp + (bm * 2 + bn) * 256;
    p[t] = s;
    p[128 + t] = q;
  }
}

// --------------------------- BN stats reduce + finalize (256 blocks, parallel)
__global__ __launch_bounds__(128) void stats_finalize_k(
    const float* __restrict__ Pp, const float* __restrict__ bl,
    const float* __restrict__ gamma, const float* __restrict__ beta,
    float* __restrict__ scale, float* __restrict__ shiftv)
{
  __shared__ float red_s[128];
  __shared__ float red_q[128];
  int c = blockIdx.x;                 // one column per block
  int half = c >> 7, cl = c & 127;
  int t = threadIdx.x;
  float s = 0.f, q = 0.f;
  for (int bm = t; bm < MTILES; bm += 128) {
    const float* p = Pp + (bm * 2 + half) * 256;
    s += p[cl];
    q += p[128 + cl];
  }
  red_s[t] = s; red_q[t] = q;
  __syncthreads();
#pragma unroll
  for (int off = 64; off > 0; off >>= 1) {
    if (t < off) {
      red_s[t] += red_s[t + off];
      red_q[t] += red_q[t + off];
    }
    __syncthreads();
  }
  if (t == 0) {
    s = red_s[0]; q = red_q[0];
    float bc = bl[c];
    s -= (float)(N_PAD - N_NODESC) * bc;
    q -= (float)(N_PAD - N_NODESC) * bc * bc;
    const float invN = 1.0f / (float)N_NODESC;
    float mu = s * invN;
    float var = q * invN - mu * mu;
    float rsq = rsqrtf(var + 1e-5f);
    float sc = gamma[c] * rsq;
    scale[c] = sc;
    shiftv[c] = beta[c] - mu * sc;
  }
}

// ---------------------------------------------------------------- mean pooling
__device__ __forceinline__ int lower_bound_g(const int* gid, int n, int g)
{
  int lo = 0, hi = n;
  while (lo < hi) {
    int mid = (lo + hi) >> 1;
    if (gid[mid] < g) lo = mid + 1; else hi = mid;
  }
  return lo;
}

// 1 block/graph, 8 waves stride rows; BN+relu inline (layer-4 params);
// slice-major Y16.
__global__ __launch_bounds__(512) void pool_k(
    const unsigned short* __restrict__ Y16, const int* __restrict__ gid,
    const float* __restrict__ scale, const float* __restrict__ shiftv,
    float* __restrict__ gpool)
{
  __shared__ float red[8 * 256];
  int g = blockIdx.x;
  int lo = lower_bound_g(gid, N_NODESC, g);
  int hi = lower_bound_g(gid, N_NODESC, g + 1);
  int t = threadIdx.x;
  int w = t >> 6, lane = t & 63;
  int col = lane * 4;
  long ybase = (long)(col >> 5) * SLAB + (col & 31);
  float4 sc = *(const float4*)(scale + col);
  float4 sh = *(const float4*)(shiftv + col);
  float a0 = 0.f, a1 = 0.f, a2 = 0.f, a3 = 0.f;
  for (int r = lo + w; r < hi; r += 8) {
    ushort4 u = *(const ushort4*)(Y16 + ybase + (long)r * 32);
    a0 += fmaxf(0.f, h2f(u.x) * sc.x + sh.x);
    a1 += fmaxf(0.f, h2f(u.y) * sc.y + sh.y);
    a2 += fmaxf(0.f, h2f(u.z) * sc.z + sh.z);
    a3 += fmaxf(0.f, h2f(u.w) * sc.w + sh.w);
  }
  *(float4*)&red[w * 256 + col] = make_float4(a0, a1, a2, a3);
  __syncthreads();
  if (t < 256) {
    float s = 0.f;
#pragma unroll
    for (int j = 0; j < 8; ++j) s += red[j * 256 + t];
    int c = hi - lo;
    gpool[g * 256 + t] = s / (float)(c > 0 ? c : 1);
  }
}

// ---------------------------------------------------------------- final proj
__global__ __launch_bounds__(128) void final_k(
    const float* __restrict__ gpool, const float* __restrict__ Wp,
    const float* __restrict__ bp, float* __restrict__ out)
{
  __shared__ float gr[256];
  int g = blockIdx.x, t = threadIdx.x;
  gr[t] = gpool[g * 256 + t];
  gr[t + 128] = gpool[g * 256 + t + 128];
  __syncthreads();
  float acc = bp[t];
#pragma unroll 8
  for (int k = 0; k < 256; ++k) acc += gr[k] * Wp[k * 128 + t];
  out[g * 128 + t] = acc;
}

// ---------------------------------------------------------------- launcher
extern "C" void kernel_launch(void* const* d_in, const int* in_sizes, int n_in,
                              void* d_out, int out_size, void* d_ws, size_t ws_size,
                              hipStream_t stream)
{
  (void)in_sizes; (void)n_in; (void)out_size; (void)ws_size;
  const int* nfeat = (const int*)d_in[0];
  const int* efeat = (const int*)d_in[1];
  const int* src = (const int*)d_in[2];
  const int* dst = (const int*)d_in[3];
  const int* gid = (const int*)d_in[4];
  const float* atom_emb = (const float*)d_in[5];
  const float* edge_emb = (const float*)d_in[6];
  const float* W = (const float*)d_in[7];
  const float* b = (const float*)d_in[8];
  const float* gamma = (const float*)d_in[9];
  const float* beta = (const float*)d_in[10];
  const float* Wp = (const float*)d_in[11];
  const float* bp = (const float*)d_in[12];
  float* out = (float*)d_out;

  char* ws = (char*)d_ws;
  unsigned short* h16 = (unsigned short*)ws; ws += (size_t)N_PAD * 512;
  unsigned short* Y16 = (unsigned short*)ws; ws += (size_t)N_PAD * 512;
  unsigned short* X16 = (unsigned short*)ws; ws += (size_t)N_PAD * 512;
  unsigned short* Wt = (unsigned short*)ws; ws += 5 * 65536 * 2;
  int* csrc = (int*)ws; ws += 3200000;
  int* ceid = (int*)ws; ws += 3200000;
  int* row_start = (int*)ws; ws += 200064;
  int* degs_i = (int*)ws; ws += 200064;
  int* fill = (int*)ws; ws += 200064;
  unsigned char* cntc = (unsigned char*)ws; ws += 1200128;
  float* Pp = (float*)ws; ws += MTILES * 2 * 256 * 4;
  float* scale = (float*)ws; ws += 1024;
  float* shiftv = (float*)ws; ws += 1024;
  float* gpool = (float*)ws; ws += 131072;

  hipMemsetAsync(degs_i, 0, 200000, stream);
  hipMemsetAsync(fill, 0, 200000, stream);
  // zero X16 pad rows in each slice slab so GEMM pad output is exactly b[c]
  for (int s = 0; s < 8; ++s)
    hipMemsetAsync(X16 + (size_t)s * SLAB + (size_t)N_NODESC * 32, 0,
                   (size_t)(N_PAD - N_NODESC) * 64, stream);

  wprep_k<<<1280, 256, 0, stream>>>(W, Wt);
  atom_encode_k<<<12500, 256, 0, stream>>>(nfeat, atom_emb, h16);
  deg_k<<<3125, 256, 0, stream>>>(dst, degs_i);
  scan_k<<<1, 1024, 0, stream>>>(degs_i, row_start, N_NODESC);
  scatter_k<<<3125, 256, 0, stream>>>(src, dst, row_start, fill, csrc, ceid);
  cnt_k<<<196, 256, 0, stream>>>(ceid, row_start, efeat, cntc);

  // layer 0 aggregate: atom-encoded h16, no BN
  aggregate_t<0><<<100000, 256, 0, stream>>>(h16, edge_emb, csrc, row_start,
                                             cntc, nullptr, nullptr, X16);
  for (int l = 0; l < 5; ++l) {
    gemm_k<<<dim3(MTILES, 2), 256, 0, stream>>>(X16, Wt + l * 65536, b + l * 256,
                                                Y16, Pp);
    stats_finalize_k<<<256, 128, 0, stream>>>(Pp, b + l * 256, gamma + l * 256,
                                              beta + l * 256, scale, shiftv);
    if (l < 4)
      aggregate_t<1><<<100000, 256, 0, stream>>>(Y16, edge_emb + (l + 1) * 6144,
                                                 csrc, row_start, cntc, scale,
                                                 shiftv, X16);
  }

  pool_k<<<128, 512, 0, stream>>>(Y16, gid, scale, shiftv, gpool);
  final_k<<<128, 128, 0, stream>>>(gpool, Wp, bp, out);
}

// Round 13
// 879.379 us; speedup vs baseline: 2.4037x; 2.4037x over previous
//
#include <hip/hip_runtime.h>

#define N_NODESC 50000
#define N_PAD 50176          // 392 * 128
#define N_EDGESC 800000
#define N_GRAPHSC 128
#define EMBEDC 256
#define MTILES 392
#define SLAB ((long)N_PAD * 32)   // halves per 32-col slice slab

typedef __attribute__((ext_vector_type(8))) _Float16 hf8;
typedef __attribute__((ext_vector_type(4))) float fx4;
typedef __attribute__((ext_vector_type(4))) unsigned int ux4;

__device__ __forceinline__ float h2f(unsigned short u) {
  _Float16 h = *(_Float16*)&u;
  return (float)h;
}
__device__ __forceinline__ unsigned short f2h(float f) {
  _Float16 h = (_Float16)f;
  return *(unsigned short*)&h;
}
__device__ __forceinline__ unsigned int packh2(float lo, float hi) {
  return (unsigned int)f2h(lo) | ((unsigned int)f2h(hi) << 16);
}

// ------------------------------------------- atom encoder (slice-major h16)
__global__ __launch_bounds__(256) void atom_encode_k(
    const int* __restrict__ nfeat, const float* __restrict__ atom_emb,
    unsigned short* __restrict__ h16)
{
  int w = threadIdx.x >> 6, lane = threadIdx.x & 63;
  int n = blockIdx.x * 4 + w;
  if (n >= N_NODESC) return;
  const int* nf = nfeat + n * 9;
  float ax = 0.f, ay = 0.f, az = 0.f, aw = 0.f;
#pragma unroll
  for (int c = 0; c < 9; ++c) {
    int idx = nf[c];
    const float4* row = (const float4*)(atom_emb + (c * 128 + idx) * EMBEDC);
    float4 v = row[lane];
    ax += v.x; ay += v.y; az += v.z; aw += v.w;
  }
  ushort4 o;
  o.x = f2h(ax); o.y = f2h(ay); o.z = f2h(az); o.w = f2h(aw);
  int col = lane * 4;
  *(ushort4*)(h16 + (long)(col >> 5) * SLAB + (long)n * 32 + (col & 31)) = o;
}

// ---------------------------------------------------------------- degree count
__global__ __launch_bounds__(256) void deg_k(
    const int* __restrict__ dst, int* __restrict__ degs)
{
  int e = blockIdx.x * 256 + threadIdx.x;
  if (e >= N_EDGESC) return;
  atomicAdd(&degs[dst[e]], 1);
}

// ---------------------------------------------------------------- exclusive scan
__global__ __launch_bounds__(1024) void scan_k(
    const int* __restrict__ deg, int* __restrict__ row_start, int n)
{
  __shared__ int buf[1024];
  __shared__ int carry;
  int t = threadIdx.x;
  if (t == 0) carry = 0;
  __syncthreads();
  for (int base = 0; base < n; base += 8192) {
    int loc[8];
    int s = 0;
    int idx0 = base + t * 8;
#pragma unroll
    for (int i = 0; i < 8; ++i) {
      int v = (idx0 + i < n) ? deg[idx0 + i] : 0;
      loc[i] = v; s += v;
    }
    buf[t] = s;
    __syncthreads();
    for (int off = 1; off < 1024; off <<= 1) {
      int add = (t >= off) ? buf[t - off] : 0;
      __syncthreads();
      buf[t] += add;
      __syncthreads();
    }
    int excl = buf[t] - s;
    int run = carry + excl;
#pragma unroll
    for (int i = 0; i < 8; ++i) {
      if (idx0 + i < n) row_start[idx0 + i] = run;
      run += loc[i];
    }
    __syncthreads();
    if (t == 1023) carry += buf[1023];
    __syncthreads();
  }
  if (t == 0) row_start[n] = carry;
}

// ---------------------------------------------------------------- CSR scatter
__global__ __launch_bounds__(256) void scatter_k(
    const int* __restrict__ src, const int* __restrict__ dst,
    const int* __restrict__ row_start, int* __restrict__ fill,
    int* __restrict__ csrc, int* __restrict__ ceid)
{
  int e = blockIdx.x * 256 + threadIdx.x;
  if (e >= N_EDGESC) return;
  int d = dst[e];
  int pos = row_start[d] + atomicAdd(&fill[d], 1);
  csrc[pos] = src[e];
  ceid[pos] = e;
}

// ------------------------------- per-node edge-feature histogram (uchar out)
__global__ __launch_bounds__(256) void cnt_k(
    const int* __restrict__ ceid, const int* __restrict__ row_start,
    const int* __restrict__ efeat, unsigned char* __restrict__ cntc)
{
  __shared__ int lc[256 * 25];
  int t = threadIdx.x;
  int n = blockIdx.x * 256 + t;
  int base = t * 25;
#pragma unroll
  for (int j = 0; j < 24; ++j) lc[base + j] = 0;
  if (n >= N_NODESC) return;
  int s0 = row_start[n], s1 = row_start[n + 1];
  for (int e = s0; e < s1; ++e) {
    int eid = ceid[e];
    int v0 = efeat[eid * 3 + 0];
    int v1 = efeat[eid * 3 + 1];
    int v2 = efeat[eid * 3 + 2];
    lc[base + v0]++;
    lc[base + 8 + v1]++;
    lc[base + 16 + v2]++;
  }
#pragma unroll
  for (int j = 0; j < 24; ++j) cntc[n * 24 + j] = (unsigned char)lc[base + j];
}

// ------------------------------------------------ W transpose + fp16 convert
__global__ __launch_bounds__(256) void wprep_k(
    const float* __restrict__ W, unsigned short* __restrict__ Wt)
{
  int tid = blockIdx.x * 256 + threadIdx.x;     // 5*65536
  int l = tid >> 16, r = tid & 65535;
  int n = r >> 8, k = r & 255;
  float w = W[(long)l * 65536 + k * 256 + n];
  Wt[tid] = f2h(w);                             // tid == l*65536 + n*256 + k
}

// ---------------------------------------------------------------- aggregation
// XCD-sliced (slice = blockIdx%8 -> slab L2-resident per XCD), VALU-lean:
// wave = 4 nodes x 16 lanes (4 edge-groups x 4 chunks of 16B). Histogram bins
// split across edge-groups, packed-fp16 FMA, merged pre-reduce. 2-level shfl.
template<int FUSE_BN>
__device__ __forceinline__ void bnacc(const uint4 u, float* a,
                                      const hf8 scv, const hf8 shv)
{
  union { uint4 u4; hf8 h8; } cv;
  cv.u4 = u;
  hf8 y = cv.h8;
  if (FUSE_BN) {
    y = y * scv + shv;                       // v_pk_fma_f16 x4
    y = __builtin_elementwise_max(y, (hf8)0);// v_pk_max_f16 x4
  }
#pragma unroll
  for (int k = 0; k < 8; ++k) a[k] += (float)y[k];
}

template<int FUSE_BN>
__global__ __launch_bounds__(256) void aggregate_t(
    const unsigned short* __restrict__ tab_base, const float* __restrict__ emb_l,
    const int* __restrict__ csrc, const int* __restrict__ row_start,
    const unsigned char* __restrict__ cntc,
    const unsigned short* __restrict__ sc16,
    const unsigned short* __restrict__ sh16,
    unsigned short* __restrict__ X16)
{
  __shared__ unsigned short semb[24 * 32];       // this slice of edge emb, fp16
  int bid = blockIdx.x;
  int s = bid & 7;                               // slice == XCD (heuristic)
  int grp = bid >> 3;
  for (int i = threadIdx.x; i < 24 * 16; i += 256) {
    int j = i >> 4, cc = (i & 15) * 2;
    float2 f = *(const float2*)&emb_l[j * 256 + s * 32 + cc];
    *(unsigned int*)&semb[j * 32 + cc] = packh2(f.x, f.y);
  }
  __syncthreads();
  int lane = threadIdx.x & 63;
  int w = threadIdx.x >> 6;
  int nd = lane >> 4;            // node within wave (4)
  int g = (lane >> 2) & 3;       // edge group (4)
  int q = lane & 3;              // 16B chunk (4)
  int n = grp * 16 + w * 4 + nd; // 3125*16 == 50000 exactly
  const unsigned short* tab = tab_base + (long)s * SLAB;
  hf8 scv = (hf8)0, shv = (hf8)0;
  if (FUSE_BN) {
    scv = *(const hf8*)(sc16 + s * 32 + q * 8);
    shv = *(const hf8*)(sh16 + s * 32 + q * 8);
  }
  float a[8] = {0.f, 0.f, 0.f, 0.f, 0.f, 0.f, 0.f, 0.f};
  int s0 = row_start[n], s1 = row_start[n + 1];
  if (g == 0) {                                  // self row (once, pre-reduce)
    uint4 u = *(const uint4*)(tab + (long)n * 32 + q * 8);
    bnacc<FUSE_BN>(u, a, scv, shv);
  }
  int e = s0 + g;
  for (; e + 4 < s1; e += 8) {                   // 2 edges in flight per lane
    int i0 = __builtin_nontemporal_load(csrc + e);
    int i1 = __builtin_nontemporal_load(csrc + e + 4);
    uint4 u0 = *(const uint4*)(tab + (long)i0 * 32 + q * 8);
    uint4 u1 = *(const uint4*)(tab + (long)i1 * 32 + q * 8);
    bnacc<FUSE_BN>(u0, a, scv, shv);
    bnacc<FUSE_BN>(u1, a, scv, shv);
  }
  if (e < s1) {
    int i0 = __builtin_nontemporal_load(csrc + e);
    uint4 u = *(const uint4*)(tab + (long)i0 * 32 + q * 8);
    bnacc<FUSE_BN>(u, a, scv, shv);
  }
  // histogram: group g handles bins {g, g+4, ..., g+20}; packed fp16 fma
  {
    const unsigned int* cw = (const unsigned int*)(cntc + n * 24);
    hf8 he = (hf8)0;
#pragma unroll
    for (int m = 0; m < 6; ++m) {
      unsigned int cu = __builtin_nontemporal_load(cw + m);
      int cj = (cu >> (g * 8)) & 255;
      int j = g + m * 4;
      hf8 ev = *(const hf8*)&semb[j * 32 + q * 8];
      _Float16 fch = (_Float16)(float)cj;
      hf8 fcv = {fch, fch, fch, fch, fch, fch, fch, fch};
      he = he + ev * fcv;                        // v_pk_fma_f16 x4
    }
#pragma unroll
    for (int k = 0; k < 8; ++k) a[k] += (float)he[k];
  }
  // reduce over the 4 edge-groups (lane bits 2..3)
#pragma unroll
  for (int k = 0; k < 8; ++k) {
    a[k] += __shfl_xor(a[k], 4);
    a[k] += __shfl_xor(a[k], 8);
  }
  if (g == 0) {                                  // 4 lanes/node write 64B
    float inv = 1.0f / (float)(s1 - s0 + 1);
    ux4 o;
    o.x = packh2(a[0] * inv, a[1] * inv);
    o.y = packh2(a[2] * inv, a[3] * inv);
    o.z = packh2(a[4] * inv, a[5] * inv);
    o.w = packh2(a[6] * inv, a[7] * inv);
    __builtin_nontemporal_store(o,
        (ux4*)(X16 + (long)s * SLAB + (long)n * 32 + q * 8));
  }
}

// ---------------------------------------------------------------- MFMA GEMM fp16
// Y16 = fp16(X @ W + b); slice-major X/Y; per-block BN partials (no atomics)
__global__ __launch_bounds__(256) void gemm_k(
    const unsigned short* __restrict__ X16, const unsigned short* __restrict__ Bt,
    const float* __restrict__ bl, unsigned short* __restrict__ Y16,
    float* __restrict__ Pp)
{
  __shared__ unsigned short As[128 * 72];
  __shared__ unsigned short Bs[128 * 72];
  __shared__ float red_s[256];
  __shared__ float red_q[256];

  int t = threadIdx.x;
  int bm = blockIdx.x, bn = blockIdx.y;
  int row0 = bm * 128, nc0 = bn * 128;
  int w = t >> 6, l = t & 63;
  int wr = w >> 1, wc = w & 1;
  int lr = l & 15, lk = l >> 4;

  fx4 acc[4][4];
#pragma unroll
  for (int i = 0; i < 4; ++i)
#pragma unroll
    for (int j = 0; j < 4; ++j) acc[i][j] = (fx4){0.f, 0.f, 0.f, 0.f};

  for (int kc = 0; kc < 256; kc += 64) {
    __syncthreads();
#pragma unroll
    for (int q = 0; q < 2; ++q) {
      int id = q * 256 + t;
      int r = id >> 2, c16 = (id & 3) << 4;
      int ktot = kc + c16;
      long gA = (long)(ktot >> 5) * SLAB + (long)(row0 + r) * 32 + (ktot & 31);
      long gB = (long)(nc0 + r) * 256 + ktot;
      *(uint4*)&As[r * 72 + c16] = *(const uint4*)(X16 + gA);
      *(uint4*)&As[r * 72 + c16 + 8] = *(const uint4*)(X16 + gA + 8);
      *(uint4*)&Bs[r * 72 + c16] = *(const uint4*)(Bt + gB);
      *(uint4*)&Bs[r * 72 + c16 + 8] = *(const uint4*)(Bt + gB + 8);
    }
    __syncthreads();
#pragma unroll
    for (int ks = 0; ks < 2; ++ks) {
      int ko = ks * 32 + lk * 8;
      hf8 af[4], bf[4];
#pragma unroll
      for (int f = 0; f < 4; ++f) {
        af[f] = *(const hf8*)&As[(wr * 64 + f * 16 + lr) * 72 + ko];
        bf[f] = *(const hf8*)&Bs[(wc * 64 + f * 16 + lr) * 72 + ko];
      }
#pragma unroll
      for (int fm = 0; fm < 4; ++fm)
#pragma unroll
        for (int fn = 0; fn < 4; ++fn)
          acc[fm][fn] = __builtin_amdgcn_mfma_f32_16x16x32_f16(
              af[fm], bf[fn], acc[fm][fn], 0, 0, 0);
    }
  }

  float bcol[4];
#pragma unroll
  for (int fn = 0; fn < 4; ++fn) bcol[fn] = bl[nc0 + wc * 64 + fn * 16 + lr];
  float sp[4] = {0.f, 0.f, 0.f, 0.f}, qp[4] = {0.f, 0.f, 0.f, 0.f};
#pragma unroll
  for (int fm = 0; fm < 4; ++fm)
#pragma unroll
    for (int fn = 0; fn < 4; ++fn) {
      int cl = wc * 64 + fn * 16 + lr;
      int col = nc0 + cl;
      long ybase = (long)(col >> 5) * SLAB + (col & 31);
#pragma unroll
      for (int j = 0; j < 4; ++j) {
        int rl = wr * 64 + fm * 16 + lk * 4 + j;
        float v = acc[fm][fn][j] + bcol[fn];
        Y16[ybase + (long)(row0 + rl) * 32] = f2h(v);
        sp[fn] += v; qp[fn] += v * v;
      }
    }
#pragma unroll
  for (int fn = 0; fn < 4; ++fn) {
    sp[fn] += __shfl_xor(sp[fn], 16);
    sp[fn] += __shfl_xor(sp[fn], 32);
    qp[fn] += __shfl_xor(qp[fn], 16);
    qp[fn] += __shfl_xor(qp[fn], 32);
  }
  if (lk == 0) {
#pragma unroll
    for (int fn = 0; fn < 4; ++fn) {
      red_s[w * 64 + fn * 16 + lr] = sp[fn];
      red_q[w * 64 + fn * 16 + lr] = qp[fn];
    }
  }
  __syncthreads();
  if (t < 128) {
    float s = red_s[t] + red_s[128 + t];
    float q = red_q[t] + red_q[128 + t];
    float* p = Pp + (bm * 2 + bn) * 256;
    p[t] = s;
    p[128 + t] = q;
  }
}

// --------------------------- BN stats reduce + finalize (256 blocks, parallel)
__global__ __launch_bounds__(128) void stats_finalize_k(
    const float* __restrict__ Pp, const float* __restrict__ bl,
    const float* __restrict__ gamma, const float* __restrict__ beta,
    float* __restrict__ scale, float* __restrict__ shiftv,
    unsigned short* __restrict__ sc16, unsigned short* __restrict__ sh16)
{
  __shared__ float red_s[128];
  __shared__ float red_q[128];
  int c = blockIdx.x;                 // one column per block
  int half = c >> 7, cl = c & 127;
  int t = threadIdx.x;
  float s = 0.f, q = 0.f;
  for (int bm = t; bm < MTILES; bm += 128) {
    const float* p = Pp + (bm * 2 + half) * 256;
    s += p[cl];
    q += p[128 + cl];
  }
  red_s[t] = s; red_q[t] = q;
  __syncthreads();
#pragma unroll
  for (int off = 64; off > 0; off >>= 1) {
    if (t < off) {
      red_s[t] += red_s[t + off];
      red_q[t] += red_q[t + off];
    }
    __syncthreads();
  }
  if (t == 0) {
    s = red_s[0]; q = red_q[0];
    float bc = bl[c];
    s -= (float)(N_PAD - N_NODESC) * bc;
    q -= (float)(N_PAD - N_NODESC) * bc * bc;
    const float invN = 1.0f / (float)N_NODESC;
    float mu = s * invN;
    float var = q * invN - mu * mu;
    float rsq = rsqrtf(var + 1e-5f);
    float sc = gamma[c] * rsq;
    float sh = beta[c] - mu * sc;
    scale[c] = sc;
    shiftv[c] = sh;
    sc16[c] = f2h(sc);
    sh16[c] = f2h(sh);
  }
}

// ---------------------------------------------------------------- mean pooling
__device__ __forceinline__ int lower_bound_g(const int* gid, int n, int g)
{
  int lo = 0, hi = n;
  while (lo < hi) {
    int mid = (lo + hi) >> 1;
    if (gid[mid] < g) lo = mid + 1; else hi = mid;
  }
  return lo;
}

// 1 block/graph, 8 waves stride rows; BN+relu inline (layer-4 params);
// slice-major Y16.
__global__ __launch_bounds__(512) void pool_k(
    const unsigned short* __restrict__ Y16, const int* __restrict__ gid,
    const float* __restrict__ scale, const float* __restrict__ shiftv,
    float* __restrict__ gpool)
{
  __shared__ float red[8 * 256];
  int g = blockIdx.x;
  int lo = lower_bound_g(gid, N_NODESC, g);
  int hi = lower_bound_g(gid, N_NODESC, g + 1);
  int t = threadIdx.x;
  int w = t >> 6, lane = t & 63;
  int col = lane * 4;
  long ybase = (long)(col >> 5) * SLAB + (col & 31);
  float4 sc = *(const float4*)(scale + col);
  float4 sh = *(const float4*)(shiftv + col);
  float a0 = 0.f, a1 = 0.f, a2 = 0.f, a3 = 0.f;
  for (int r = lo + w; r < hi; r += 8) {
    ushort4 u = *(const ushort4*)(Y16 + ybase + (long)r * 32);
    a0 += fmaxf(0.f, h2f(u.x) * sc.x + sh.x);
    a1 += fmaxf(0.f, h2f(u.y) * sc.y + sh.y);
    a2 += fmaxf(0.f, h2f(u.z) * sc.z + sh.z);
    a3 += fmaxf(0.f, h2f(u.w) * sc.w + sh.w);
  }
  *(float4*)&red[w * 256 + col] = make_float4(a0, a1, a2, a3);
  __syncthreads();
  if (t < 256) {
    float s = 0.f;
#pragma unroll
    for (int j = 0; j < 8; ++j) s += red[j * 256 + t];
    int c = hi - lo;
    gpool[g * 256 + t] = s / (float)(c > 0 ? c : 1);
  }
}

// ---------------------------------------------------------------- final proj
__global__ __launch_bounds__(128) void final_k(
    const float* __restrict__ gpool, const float* __restrict__ Wp,
    const float* __restrict__ bp, float* __restrict__ out)
{
  __shared__ float gr[256];
  int g = blockIdx.x, t = threadIdx.x;
  gr[t] = gpool[g * 256 + t];
  gr[t + 128] = gpool[g * 256 + t + 128];
  __syncthreads();
  float acc = bp[t];
#pragma unroll 8
  for (int k = 0; k < 256; ++k) acc += gr[k] * Wp[k * 128 + t];
  out[g * 128 + t] = acc;
}

// ---------------------------------------------------------------- launcher
extern "C" void kernel_launch(void* const* d_in, const int* in_sizes, int n_in,
                              void* d_out, int out_size, void* d_ws, size_t ws_size,
                              hipStream_t stream)
{
  (void)in_sizes; (void)n_in; (void)out_size; (void)ws_size;
  const int* nfeat = (const int*)d_in[0];
  const int* efeat = (const int*)d_in[1];
  const int* src = (const int*)d_in[2];
  const int* dst = (const int*)d_in[3];
  const int* gid = (const int*)d_in[4];
  const float* atom_emb = (const float*)d_in[5];
  const float* edge_emb = (const float*)d_in[6];
  const float* W = (const float*)d_in[7];
  const float* b = (const float*)d_in[8];
  const float* gamma = (const float*)d_in[9];
  const float* beta = (const float*)d_in[10];
  const float* Wp = (const float*)d_in[11];
  const float* bp = (const float*)d_in[12];
  float* out = (float*)d_out;

  char* ws = (char*)d_ws;
  unsigned short* h16 = (unsigned short*)ws; ws += (size_t)N_PAD * 512;
  unsigned short* Y16 = (unsigned short*)ws; ws += (size_t)N_PAD * 512;
  unsigned short* X16 = (unsigned short*)ws; ws += (size_t)N_PAD * 512;
  unsigned short* Wt = (unsigned short*)ws; ws += 5 * 65536 * 2;
  int* csrc = (int*)ws; ws += 3200000;
  int* ceid = (int*)ws; ws += 3200000;
  int* row_start = (int*)ws; ws += 200064;
  int* degs_i = (int*)ws; ws += 200064;
  int* fill = (int*)ws; ws += 200064;
  unsigned char* cntc = (unsigned char*)ws; ws += 1200128;
  float* Pp = (float*)ws; ws += MTILES * 2 * 256 * 4;
  float* scale = (float*)ws; ws += 1024;
  float* shiftv = (float*)ws; ws += 1024;
  unsigned short* sc16 = (unsigned short*)ws; ws += 512;
  unsigned short* sh16 = (unsigned short*)ws; ws += 512;
  float* gpool = (float*)ws; ws += 131072;

  hipMemsetAsync(degs_i, 0, 200000, stream);
  hipMemsetAsync(fill, 0, 200000, stream);
  // zero X16 pad rows in each slice slab so GEMM pad output is exactly b[c]
  for (int s = 0; s < 8; ++s)
    hipMemsetAsync(X16 + (size_t)s * SLAB + (size_t)N_NODESC * 32, 0,
                   (size_t)(N_PAD - N_NODESC) * 64, stream);

  wprep_k<<<1280, 256, 0, stream>>>(W, Wt);
  atom_encode_k<<<12500, 256, 0, stream>>>(nfeat, atom_emb, h16);
  deg_k<<<3125, 256, 0, stream>>>(dst, degs_i);
  scan_k<<<1, 1024, 0, stream>>>(degs_i, row_start, N_NODESC);
  scatter_k<<<3125, 256, 0, stream>>>(src, dst, row_start, fill, csrc, ceid);
  cnt_k<<<196, 256, 0, stream>>>(ceid, row_start, efeat, cntc);

  // layer 0 aggregate: atom-encoded h16, no BN
  aggregate_t<0><<<25000, 256, 0, stream>>>(h16, edge_emb, csrc, row_start,
                                            cntc, nullptr, nullptr, X16);
  for (int l = 0; l < 5; ++l) {
    gemm_k<<<dim3(MTILES, 2), 256, 0, stream>>>(X16, Wt + l * 65536, b + l * 256,
                                                Y16, Pp);
    stats_finalize_k<<<256, 128, 0, stream>>>(Pp, b + l * 256, gamma + l * 256,
                                              beta + l * 256, scale, shiftv,
                                              sc16, sh16);
    if (l < 4)
      aggregate_t<1><<<25000, 256, 0, stream>>>(Y16, edge_emb + (l + 1) * 6144,
                                                csrc, row_start, cntc, sc16,
                                                sh16, X16);
  }

  pool_k<<<128, 512, 0, stream>>>(Y16, gid, scale, shiftv, gpool);
  final_k<<<128, 128, 0, stream>>>(gpool, Wp, bp, out);
}

// Round 14
// 724.512 us; speedup vs baseline: 2.9175x; 1.2138x over previous
//
#include <hip/hip_runtime.h>

#define N_NODESC 50000
#define N_PAD 50176          // 392 * 128
#define N_EDGESC 800000
#define N_GRAPHSC 128
#define EMBEDC 256
#define MTILES 392
#define SLAB ((long)N_PAD * 32)   // halves per 32-col slice slab

typedef __attribute__((ext_vector_type(8))) _Float16 hf8;
typedef __attribute__((ext_vector_type(4))) float fx4;

__device__ __forceinline__ float h2f(unsigned short u) {
  _Float16 h = *(_Float16*)&u;
  return (float)h;
}
__device__ __forceinline__ unsigned short f2h(float f) {
  _Float16 h = (_Float16)f;
  return *(unsigned short*)&h;
}
__device__ __forceinline__ unsigned int packh2(float lo, float hi) {
  return (unsigned int)f2h(lo) | ((unsigned int)f2h(hi) << 16);
}

// ------------------------------------------- atom encoder (slice-major h16)
__global__ __launch_bounds__(256) void atom_encode_k(
    const int* __restrict__ nfeat, const float* __restrict__ atom_emb,
    unsigned short* __restrict__ h16)
{
  int w = threadIdx.x >> 6, lane = threadIdx.x & 63;
  int n = blockIdx.x * 4 + w;
  if (n >= N_NODESC) return;
  const int* nf = nfeat + n * 9;
  float ax = 0.f, ay = 0.f, az = 0.f, aw = 0.f;
#pragma unroll
  for (int c = 0; c < 9; ++c) {
    int idx = nf[c];
    const float4* row = (const float4*)(atom_emb + (c * 128 + idx) * EMBEDC);
    float4 v = row[lane];
    ax += v.x; ay += v.y; az += v.z; aw += v.w;
  }
  ushort4 o;
  o.x = f2h(ax); o.y = f2h(ay); o.z = f2h(az); o.w = f2h(aw);
  int col = lane * 4;
  *(ushort4*)(h16 + (long)(col >> 5) * SLAB + (long)n * 32 + (col & 31)) = o;
}

// ---------------------------------------------------------------- degree count
__global__ __launch_bounds__(256) void deg_k(
    const int* __restrict__ dst, int* __restrict__ degs)
{
  int e = blockIdx.x * 256 + threadIdx.x;
  if (e >= N_EDGESC) return;
  atomicAdd(&degs[dst[e]], 1);
}

// ---------------------------------------------------------------- exclusive scan
__global__ __launch_bounds__(1024) void scan_k(
    const int* __restrict__ deg, int* __restrict__ row_start, int n)
{
  __shared__ int buf[1024];
  __shared__ int carry;
  int t = threadIdx.x;
  if (t == 0) carry = 0;
  __syncthreads();
  for (int base = 0; base < n; base += 8192) {
    int loc[8];
    int s = 0;
    int idx0 = base + t * 8;
#pragma unroll
    for (int i = 0; i < 8; ++i) {
      int v = (idx0 + i < n) ? deg[idx0 + i] : 0;
      loc[i] = v; s += v;
    }
    buf[t] = s;
    __syncthreads();
    for (int off = 1; off < 1024; off <<= 1) {
      int add = (t >= off) ? buf[t - off] : 0;
      __syncthreads();
      buf[t] += add;
      __syncthreads();
    }
    int excl = buf[t] - s;
    int run = carry + excl;
#pragma unroll
    for (int i = 0; i < 8; ++i) {
      if (idx0 + i < n) row_start[idx0 + i] = run;
      run += loc[i];
    }
    __syncthreads();
    if (t == 1023) carry += buf[1023];
    __syncthreads();
  }
  if (t == 0) row_start[n] = carry;
}

// ---------------------------------------------------------------- CSR scatter
__global__ __launch_bounds__(256) void scatter_k(
    const int* __restrict__ src, const int* __restrict__ dst,
    const int* __restrict__ row_start, int* __restrict__ fill,
    int* __restrict__ csrc, int* __restrict__ ceid)
{
  int e = blockIdx.x * 256 + threadIdx.x;
  if (e >= N_EDGESC) return;
  int d = dst[e];
  int pos = row_start[d] + atomicAdd(&fill[d], 1);
  csrc[pos] = src[e];
  ceid[pos] = e;
}

// ------------------------------- per-node edge-feature histogram (uchar out)
__global__ __launch_bounds__(256) void cnt_k(
    const int* __restrict__ ceid, const int* __restrict__ row_start,
    const int* __restrict__ efeat, unsigned char* __restrict__ cntc)
{
  __shared__ int lc[256 * 25];
  int t = threadIdx.x;
  int n = blockIdx.x * 256 + t;
  int base = t * 25;
#pragma unroll
  for (int j = 0; j < 24; ++j) lc[base + j] = 0;
  if (n >= N_NODESC) return;
  int s0 = row_start[n], s1 = row_start[n + 1];
  for (int e = s0; e < s1; ++e) {
    int eid = ceid[e];
    int v0 = efeat[eid * 3 + 0];
    int v1 = efeat[eid * 3 + 1];
    int v2 = efeat[eid * 3 + 2];
    lc[base + v0]++;
    lc[base + 8 + v1]++;
    lc[base + 16 + v2]++;
  }
#pragma unroll
  for (int j = 0; j < 24; ++j) cntc[n * 24 + j] = (unsigned char)lc[base + j];
}

// ------------------------------------------------ W transpose + fp16 convert
__global__ __launch_bounds__(256) void wprep_k(
    const float* __restrict__ W, unsigned short* __restrict__ Wt)
{
  int tid = blockIdx.x * 256 + threadIdx.x;     // 5*65536
  int l = tid >> 16, r = tid & 65535;
  int n = r >> 8, k = r & 255;
  float w = W[(long)l * 65536 + k * 256 + n];
  Wt[tid] = f2h(w);                             // tid == l*65536 + n*256 + k
}

// ---------------------------------------------------------------- aggregation
// XCD-sliced (slice = blockIdx%8 -> slab L2-resident per XCD), VALU-lean:
// wave = 4 nodes x 16 lanes (4 edge-groups x 4 chunks of 16B). Edge values
// accumulate in packed fp16 (v_pk_add), one fp32 flush after the loop.
// Histogram bins split across edge-groups, packed-fp16 FMA, merged pre-reduce.
template<int FUSE_BN>
__device__ __forceinline__ hf8 bnval(const uint4 u, const hf8 scv, const hf8 shv)
{
  union { uint4 u4; hf8 h8; } cv;
  cv.u4 = u;
  hf8 y = cv.h8;
  if (FUSE_BN) {
    y = y * scv + shv;                        // v_pk_fma_f16 x4
    y = __builtin_elementwise_max(y, (hf8)0); // v_pk_max_f16 x4
  }
  return y;
}

template<int FUSE_BN>
__global__ __launch_bounds__(256) void aggregate_t(
    const unsigned short* __restrict__ tab_base, const float* __restrict__ emb_l,
    const int* __restrict__ csrc, const int* __restrict__ row_start,
    const unsigned char* __restrict__ cntc,
    const unsigned short* __restrict__ sc16,
    const unsigned short* __restrict__ sh16,
    unsigned short* __restrict__ X16)
{
  __shared__ unsigned short semb[24 * 32];       // this slice of edge emb, fp16
  int bid = blockIdx.x;
  int s = bid & 7;                               // slice == XCD (heuristic)
  int grp = bid >> 3;
  for (int i = threadIdx.x; i < 24 * 16; i += 256) {
    int j = i >> 4, cc = (i & 15) * 2;
    float2 f = *(const float2*)&emb_l[j * 256 + s * 32 + cc];
    *(unsigned int*)&semb[j * 32 + cc] = packh2(f.x, f.y);
  }
  __syncthreads();
  int lane = threadIdx.x & 63;
  int w = threadIdx.x >> 6;
  int nd = lane >> 4;            // node within wave (4)
  int g = (lane >> 2) & 3;       // edge group (4)
  int q = lane & 3;              // 16B chunk (4)
  int n = grp * 16 + w * 4 + nd; // 3125*16 == 50000 exactly
  const unsigned short* tab = tab_base + (long)s * SLAB;
  hf8 scv = (hf8)0, shv = (hf8)0;
  if (FUSE_BN) {
    scv = *(const hf8*)(sc16 + s * 32 + q * 8);
    shv = *(const hf8*)(sh16 + s * 32 + q * 8);
  }
  int s0 = row_start[n], s1 = row_start[n + 1];
  hf8 hacc = (hf8)0;                             // packed fp16 accumulator
  if (g == 0) {                                  // self row (once, pre-reduce)
    uint4 u = *(const uint4*)(tab + (long)n * 32 + q * 8);
    hacc = hacc + bnval<FUSE_BN>(u, scv, shv);
  }
  int e = s0 + g;
  for (; e + 4 < s1; e += 8) {                   // 2 edges in flight per lane
    int i0 = csrc[e];
    int i1 = csrc[e + 4];
    uint4 u0 = *(const uint4*)(tab + (long)i0 * 32 + q * 8);
    uint4 u1 = *(const uint4*)(tab + (long)i1 * 32 + q * 8);
    hacc = hacc + bnval<FUSE_BN>(u0, scv, shv);
    hacc = hacc + bnval<FUSE_BN>(u1, scv, shv);
  }
  if (e < s1) {
    int i0 = csrc[e];
    uint4 u = *(const uint4*)(tab + (long)i0 * 32 + q * 8);
    hacc = hacc + bnval<FUSE_BN>(u, scv, shv);
  }
  // histogram: group g handles bins {g, g+4, ..., g+20}; packed fp16 fma
  {
    const unsigned int* cw = (const unsigned int*)(cntc + n * 24);
    hf8 he = (hf8)0;
#pragma unroll
    for (int m = 0; m < 6; ++m) {
      unsigned int cu = cw[m];
      int cj = (cu >> (g * 8)) & 255;
      int j = g + m * 4;
      hf8 ev = *(const hf8*)&semb[j * 32 + q * 8];
      _Float16 fch = (_Float16)(float)cj;
      hf8 fcv = {fch, fch, fch, fch, fch, fch, fch, fch};
      he = he + ev * fcv;                        // v_pk_fma_f16 x4
    }
    hacc = hacc + he;
  }
  // single fp32 flush, then reduce over the 4 edge-groups (lane bits 2..3)
  float a[8];
#pragma unroll
  for (int k = 0; k < 8; ++k) a[k] = (float)hacc[k];
#pragma unroll
  for (int k = 0; k < 8; ++k) {
    a[k] += __shfl_xor(a[k], 4);
    a[k] += __shfl_xor(a[k], 8);
  }
  if (g == 0) {                                  // 4 lanes/node write 64B
    float inv = 1.0f / (float)(s1 - s0 + 1);
    uint4 o;
    o.x = packh2(a[0] * inv, a[1] * inv);
    o.y = packh2(a[2] * inv, a[3] * inv);
    o.z = packh2(a[4] * inv, a[5] * inv);
    o.w = packh2(a[6] * inv, a[7] * inv);
    *(uint4*)(X16 + (long)s * SLAB + (long)n * 32 + q * 8) = o;
  }
}

// ---------------------------------------------------------------- MFMA GEMM fp16
// Y16 = fp16(X @ W + b); slice-major X/Y; per-block BN partials (no atomics)
__global__ __launch_bounds__(256) void gemm_k(
    const unsigned short* __restrict__ X16, const unsigned short* __restrict__ Bt,
    const float* __restrict__ bl, unsigned short* __restrict__ Y16,
    float* __restrict__ Pp)
{
  __shared__ unsigned short As[128 * 72];
  __shared__ unsigned short Bs[128 * 72];
  __shared__ float red_s[256];
  __shared__ float red_q[256];

  int t = threadIdx.x;
  int bm = blockIdx.x, bn = blockIdx.y;
  int row0 = bm * 128, nc0 = bn * 128;
  int w = t >> 6, l = t & 63;
  int wr = w >> 1, wc = w & 1;
  int lr = l & 15, lk = l >> 4;

  fx4 acc[4][4];
#pragma unroll
  for (int i = 0; i < 4; ++i)
#pragma unroll
    for (int j = 0; j < 4; ++j) acc[i][j] = (fx4){0.f, 0.f, 0.f, 0.f};

  for (int kc = 0; kc < 256; kc += 64) {
    __syncthreads();
#pragma unroll
    for (int q = 0; q < 2; ++q) {
      int id = q * 256 + t;
      int r = id >> 2, c16 = (id & 3) << 4;
      int ktot = kc + c16;
      long gA = (long)(ktot >> 5) * SLAB + (long)(row0 + r) * 32 + (ktot & 31);
      long gB = (long)(nc0 + r) * 256 + ktot;
      *(uint4*)&As[r * 72 + c16] = *(const uint4*)(X16 + gA);
      *(uint4*)&As[r * 72 + c16 + 8] = *(const uint4*)(X16 + gA + 8);
      *(uint4*)&Bs[r * 72 + c16] = *(const uint4*)(Bt + gB);
      *(uint4*)&Bs[r * 72 + c16 + 8] = *(const uint4*)(Bt + gB + 8);
    }
    __syncthreads();
#pragma unroll
    for (int ks = 0; ks < 2; ++ks) {
      int ko = ks * 32 + lk * 8;
      hf8 af[4], bf[4];
#pragma unroll
      for (int f = 0; f < 4; ++f) {
        af[f] = *(const hf8*)&As[(wr * 64 + f * 16 + lr) * 72 + ko];
        bf[f] = *(const hf8*)&Bs[(wc * 64 + f * 16 + lr) * 72 + ko];
      }
#pragma unroll
      for (int fm = 0; fm < 4; ++fm)
#pragma unroll
        for (int fn = 0; fn < 4; ++fn)
          acc[fm][fn] = __builtin_amdgcn_mfma_f32_16x16x32_f16(
              af[fm], bf[fn], acc[fm][fn], 0, 0, 0);
    }
  }

  float bcol[4];
#pragma unroll
  for (int fn = 0; fn < 4; ++fn) bcol[fn] = bl[nc0 + wc * 64 + fn * 16 + lr];
  float sp[4] = {0.f, 0.f, 0.f, 0.f}, qp[4] = {0.f, 0.f, 0.f, 0.f};
#pragma unroll
  for (int fm = 0; fm < 4; ++fm)
#pragma unroll
    for (int fn = 0; fn < 4; ++fn) {
      int cl = wc * 64 + fn * 16 + lr;
      int col = nc0 + cl;
      long ybase = (long)(col >> 5) * SLAB + (col & 31);
#pragma unroll
      for (int j = 0; j < 4; ++j) {
        int rl = wr * 64 + fm * 16 + lk * 4 + j;
        float v = acc[fm][fn][j] + bcol[fn];
        Y16[ybase + (long)(row0 + rl) * 32] = f2h(v);
        sp[fn] += v; qp[fn] += v * v;
      }
    }
#pragma unroll
  for (int fn = 0; fn < 4; ++fn) {
    sp[fn] += __shfl_xor(sp[fn], 16);
    sp[fn] += __shfl_xor(sp[fn], 32);
    qp[fn] += __shfl_xor(qp[fn], 16);
    qp[fn] += __shfl_xor(qp[fn], 32);
  }
  if (lk == 0) {
#pragma unroll
    for (int fn = 0; fn < 4; ++fn) {
      red_s[w * 64 + fn * 16 + lr] = sp[fn];
      red_q[w * 64 + fn * 16 + lr] = qp[fn];
    }
  }
  __syncthreads();
  if (t < 128) {
    float s = red_s[t] + red_s[128 + t];
    float q = red_q[t] + red_q[128 + t];
    float* p = Pp + (bm * 2 + bn) * 256;
    p[t] = s;
    p[128 + t] = q;
  }
}

// --------------------------- BN stats reduce + finalize (256 blocks, parallel)
__global__ __launch_bounds__(128) void stats_finalize_k(
    const float* __restrict__ Pp, const float* __restrict__ bl,
    const float* __restrict__ gamma, const float* __restrict__ beta,
    float* __restrict__ scale, float* __restrict__ shiftv,
    unsigned short* __restrict__ sc16, unsigned short* __restrict__ sh16)
{
  __shared__ float red_s[128];
  __shared__ float red_q[128];
  int c = blockIdx.x;                 // one column per block
  int half = c >> 7, cl = c & 127;
  int t = threadIdx.x;
  float s = 0.f, q = 0.f;
  for (int bm = t; bm < MTILES; bm += 128) {
    const float* p = Pp + (bm * 2 + half) * 256;
    s += p[cl];
    q += p[128 + cl];
  }
  red_s[t] = s; red_q[t] = q;
  __syncthreads();
#pragma unroll
  for (int off = 64; off > 0; off >>= 1) {
    if (t < off) {
      red_s[t] += red_s[t + off];
      red_q[t] += red_q[t + off];
    }
    __syncthreads();
  }
  if (t == 0) {
    s = red_s[0]; q = red_q[0];
    float bc = bl[c];
    s -= (float)(N_PAD - N_NODESC) * bc;
    q -= (float)(N_PAD - N_NODESC) * bc * bc;
    const float invN = 1.0f / (float)N_NODESC;
    float mu = s * invN;
    float var = q * invN - mu * mu;
    float rsq = rsqrtf(var + 1e-5f);
    float sc = gamma[c] * rsq;
    float sh = beta[c] - mu * sc;
    scale[c] = sc;
    shiftv[c] = sh;
    sc16[c] = f2h(sc);
    sh16[c] = f2h(sh);
  }
}

// ---------------------------------------------------------------- mean pooling
__device__ __forceinline__ int lower_bound_g(const int* gid, int n, int g)
{
  int lo = 0, hi = n;
  while (lo < hi) {
    int mid = (lo + hi) >> 1;
    if (gid[mid] < g) lo = mid + 1; else hi = mid;
  }
  return lo;
}

// 1 block/graph, 8 waves stride rows; BN+relu inline (layer-4 params);
// slice-major Y16.
__global__ __launch_bounds__(512) void pool_k(
    const unsigned short* __restrict__ Y16, const int* __restrict__ gid,
    const float* __restrict__ scale, const float* __restrict__ shiftv,
    float* __restrict__ gpool)
{
  __shared__ float red[8 * 256];
  int g = blockIdx.x;
  int lo = lower_bound_g(gid, N_NODESC, g);
  int hi = lower_bound_g(gid, N_NODESC, g + 1);
  int t = threadIdx.x;
  int w = t >> 6, lane = t & 63;
  int col = lane * 4;
  long ybase = (long)(col >> 5) * SLAB + (col & 31);
  float4 sc = *(const float4*)(scale + col);
  float4 sh = *(const float4*)(shiftv + col);
  float a0 = 0.f, a1 = 0.f, a2 = 0.f, a3 = 0.f;
  for (int r = lo + w; r < hi; r += 8) {
    ushort4 u = *(const ushort4*)(Y16 + ybase + (long)r * 32);
    a0 += fmaxf(0.f, h2f(u.x) * sc.x + sh.x);
    a1 += fmaxf(0.f, h2f(u.y) * sc.y + sh.y);
    a2 += fmaxf(0.f, h2f(u.z) * sc.z + sh.z);
    a3 += fmaxf(0.f, h2f(u.w) * sc.w + sh.w);
  }
  *(float4*)&red[w * 256 + col] = make_float4(a0, a1, a2, a3);
  __syncthreads();
  if (t < 256) {
    float s = 0.f;
#pragma unroll
    for (int j = 0; j < 8; ++j) s += red[j * 256 + t];
    int c = hi - lo;
    gpool[g * 256 + t] = s / (float)(c > 0 ? c : 1);
  }
}

// ---------------------------------------------------------------- final proj
__global__ __launch_bounds__(128) void final_k(
    const float* __restrict__ gpool, const float* __restrict__ Wp,
    const float* __restrict__ bp, float* __restrict__ out)
{
  __shared__ float gr[256];
  int g = blockIdx.x, t = threadIdx.x;
  gr[t] = gpool[g * 256 + t];
  gr[t + 128] = gpool[g * 256 + t + 128];
  __syncthreads();
  float acc = bp[t];
#pragma unroll 8
  for (int k = 0; k < 256; ++k) acc += gr[k] * Wp[k * 128 + t];
  out[g * 128 + t] = acc;
}

// ---------------------------------------------------------------- launcher
extern "C" void kernel_launch(void* const* d_in, const int* in_sizes, int n_in,
                              void* d_out, int out_size, void* d_ws, size_t ws_size,
                              hipStream_t stream)
{
  (void)in_sizes; (void)n_in; (void)out_size; (void)ws_size;
  const int* nfeat = (const int*)d_in[0];
  const int* efeat = (const int*)d_in[1];
  const int* src = (const int*)d_in[2];
  const int* dst = (const int*)d_in[3];
  const int* gid = (const int*)d_in[4];
  const float* atom_emb = (const float*)d_in[5];
  const float* edge_emb = (const float*)d_in[6];
  const float* W = (const float*)d_in[7];
  const float* b = (const float*)d_in[8];
  const float* gamma = (const float*)d_in[9];
  const float* beta = (const float*)d_in[10];
  const float* Wp = (const float*)d_in[11];
  const float* bp = (const float*)d_in[12];
  float* out = (float*)d_out;

  char* ws = (char*)d_ws;
  unsigned short* h16 = (unsigned short*)ws; ws += (size_t)N_PAD * 512;
  unsigned short* Y16 = (unsigned short*)ws; ws += (size_t)N_PAD * 512;
  unsigned short* X16 = (unsigned short*)ws; ws += (size_t)N_PAD * 512;
  unsigned short* Wt = (unsigned short*)ws; ws += 5 * 65536 * 2;
  int* csrc = (int*)ws; ws += 3200000;
  int* ceid = (int*)ws; ws += 3200000;
  int* row_start = (int*)ws; ws += 200064;
  int* degs_i = (int*)ws; ws += 200064;
  int* fill = (int*)ws; ws += 200064;
  unsigned char* cntc = (unsigned char*)ws; ws += 1200128;
  float* Pp = (float*)ws; ws += MTILES * 2 * 256 * 4;
  float* scale = (float*)ws; ws += 1024;
  float* shiftv = (float*)ws; ws += 1024;
  unsigned short* sc16 = (unsigned short*)ws; ws += 512;
  unsigned short* sh16 = (unsigned short*)ws; ws += 512;
  float* gpool = (float*)ws; ws += 131072;

  hipMemsetAsync(degs_i, 0, 200000, stream);
  hipMemsetAsync(fill, 0, 200000, stream);
  // zero X16 pad rows in each slice slab so GEMM pad output is exactly b[c]
  for (int s = 0; s < 8; ++s)
    hipMemsetAsync(X16 + (size_t)s * SLAB + (size_t)N_NODESC * 32, 0,
                   (size_t)(N_PAD - N_NODESC) * 64, stream);

  wprep_k<<<1280, 256, 0, stream>>>(W, Wt);
  atom_encode_k<<<12500, 256, 0, stream>>>(nfeat, atom_emb, h16);
  deg_k<<<3125, 256, 0, stream>>>(dst, degs_i);
  scan_k<<<1, 1024, 0, stream>>>(degs_i, row_start, N_NODESC);
  scatter_k<<<3125, 256, 0, stream>>>(src, dst, row_start, fill, csrc, ceid);
  cnt_k<<<196, 256, 0, stream>>>(ceid, row_start, efeat, cntc);

  // layer 0 aggregate: atom-encoded h16, no BN
  aggregate_t<0><<<25000, 256, 0, stream>>>(h16, edge_emb, csrc, row_start,
                                            cntc, nullptr, nullptr, X16);
  for (int l = 0; l < 5; ++l) {
    gemm_k<<<dim3(MTILES, 2), 256, 0, stream>>>(X16, Wt + l * 65536, b + l * 256,
                                                Y16, Pp);
    stats_finalize_k<<<256, 128, 0, stream>>>(Pp, b + l * 256, gamma + l * 256,
                                              beta + l * 256, scale, shiftv,
                                              sc16, sh16);
    if (l < 4)
      aggregate_t<1><<<25000, 256, 0, stream>>>(Y16, edge_emb + (l + 1) * 6144,
                                                csrc, row_start, cntc, sc16,
                                                sh16, X16);
  }

  pool_k<<<128, 512, 0, stream>>>(Y16, gid, scale, shiftv, gpool);
  final_k<<<128, 128, 0, stream>>>(gpool, Wp, bp, out);
}

// Round 15
// 641.468 us; speedup vs baseline: 3.2952x; 1.1295x over previous
//
#include <hip/hip_runtime.h>

#define N_NODESC 50000
#define N_PAD 50176          // 392 * 128
#define N_EDGESC 800000
#define N_GRAPHSC 128
#define EMBEDC 256
#define MTILES 392
#define SLAB ((long)N_PAD * 32)   // halves per 32-col slice slab

typedef __attribute__((ext_vector_type(8))) _Float16 hf8;
typedef __attribute__((ext_vector_type(4))) float fx4;

__device__ __forceinline__ float h2f(unsigned short u) {
  _Float16 h = *(_Float16*)&u;
  return (float)h;
}
__device__ __forceinline__ unsigned short f2h(float f) {
  _Float16 h = (_Float16)f;
  return *(unsigned short*)&h;
}
__device__ __forceinline__ unsigned int packh2(float lo, float hi) {
  return (unsigned int)f2h(lo) | ((unsigned int)f2h(hi) << 16);
}

// ------------------------------------------- atom encoder (slice-major h16)
__global__ __launch_bounds__(256) void atom_encode_k(
    const int* __restrict__ nfeat, const float* __restrict__ atom_emb,
    unsigned short* __restrict__ h16)
{
  int w = threadIdx.x >> 6, lane = threadIdx.x & 63;
  int n = blockIdx.x * 4 + w;
  if (n >= N_NODESC) return;
  const int* nf = nfeat + n * 9;
  float ax = 0.f, ay = 0.f, az = 0.f, aw = 0.f;
#pragma unroll
  for (int c = 0; c < 9; ++c) {
    int idx = nf[c];
    const float4* row = (const float4*)(atom_emb + (c * 128 + idx) * EMBEDC);
    float4 v = row[lane];
    ax += v.x; ay += v.y; az += v.z; aw += v.w;
  }
  ushort4 o;
  o.x = f2h(ax); o.y = f2h(ay); o.z = f2h(az); o.w = f2h(aw);
  int col = lane * 4;
  *(ushort4*)(h16 + (long)(col >> 5) * SLAB + (long)n * 32 + (col & 31)) = o;
}

// ---------------------------------------------------------------- degree count
__global__ __launch_bounds__(256) void deg_k(
    const int* __restrict__ dst, int* __restrict__ degs)
{
  int e = blockIdx.x * 256 + threadIdx.x;
  if (e >= N_EDGESC) return;
  atomicAdd(&degs[dst[e]], 1);
}

// ---------------------------------------------------------------- exclusive scan
__global__ __launch_bounds__(1024) void scan_k(
    const int* __restrict__ deg, int* __restrict__ row_start, int n)
{
  __shared__ int buf[1024];
  __shared__ int carry;
  int t = threadIdx.x;
  if (t == 0) carry = 0;
  __syncthreads();
  for (int base = 0; base < n; base += 8192) {
    int loc[8];
    int s = 0;
    int idx0 = base + t * 8;
#pragma unroll
    for (int i = 0; i < 8; ++i) {
      int v = (idx0 + i < n) ? deg[idx0 + i] : 0;
      loc[i] = v; s += v;
    }
    buf[t] = s;
    __syncthreads();
    for (int off = 1; off < 1024; off <<= 1) {
      int add = (t >= off) ? buf[t - off] : 0;
      __syncthreads();
      buf[t] += add;
      __syncthreads();
    }
    int excl = buf[t] - s;
    int run = carry + excl;
#pragma unroll
    for (int i = 0; i < 8; ++i) {
      if (idx0 + i < n) row_start[idx0 + i] = run;
      run += loc[i];
    }
    __syncthreads();
    if (t == 1023) carry += buf[1023];
    __syncthreads();
  }
  if (t == 0) row_start[n] = carry;
}

// ---------------------------------------------------------------- CSR scatter
__global__ __launch_bounds__(256) void scatter_k(
    const int* __restrict__ src, const int* __restrict__ dst,
    const int* __restrict__ row_start, int* __restrict__ fill,
    int* __restrict__ csrc, int* __restrict__ ceid)
{
  int e = blockIdx.x * 256 + threadIdx.x;
  if (e >= N_EDGESC) return;
  int d = dst[e];
  int pos = row_start[d] + atomicAdd(&fill[d], 1);
  csrc[pos] = src[e];
  ceid[pos] = e;
}

// ------------------- per-node edge-feature histogram -> fp16 cnt/(deg+1)
// cntf[n][32]: j<24 = cnt_j/(deg+1) fp16; j>=24 = 0. Pad rows (>=50000) = 0.
__global__ __launch_bounds__(256) void cntf_k(
    const int* __restrict__ ceid, const int* __restrict__ row_start,
    const int* __restrict__ efeat, unsigned short* __restrict__ cntf)
{
  __shared__ int lc[256 * 25];
  int t = threadIdx.x;
  int n = blockIdx.x * 256 + t;          // 196*256 == 50176 == N_PAD
  int base = t * 25;
#pragma unroll
  for (int j = 0; j < 24; ++j) lc[base + j] = 0;
  float inv = 0.f;
  if (n < N_NODESC) {
    int s0 = row_start[n], s1 = row_start[n + 1];
    inv = 1.0f / (float)(s1 - s0 + 1);
    for (int e = s0; e < s1; ++e) {
      int eid = ceid[e];
      int v0 = efeat[eid * 3 + 0];
      int v1 = efeat[eid * 3 + 1];
      int v2 = efeat[eid * 3 + 2];
      lc[base + v0]++;
      lc[base + 8 + v1]++;
      lc[base + 16 + v2]++;
    }
  }
  unsigned int* o = (unsigned int*)(cntf + (long)n * 32);
#pragma unroll
  for (int j = 0; j < 12; ++j)
    o[j] = packh2((float)lc[base + 2 * j] * inv, (float)lc[base + 2 * j + 1] * inv);
#pragma unroll
  for (int j = 12; j < 16; ++j) o[j] = 0u;
}

// ------------------------------------------------ W transpose + fp16 convert
__global__ __launch_bounds__(256) void wprep_k(
    const float* __restrict__ W, unsigned short* __restrict__ Wt)
{
  int tid = blockIdx.x * 256 + threadIdx.x;     // 5*65536
  int l = tid >> 16, r = tid & 65535;
  int n = r >> 8, k = r & 255;
  float w = W[(long)l * 65536 + k * 256 + n];
  Wt[tid] = f2h(w);                             // tid == l*65536 + n*256 + k
}

// ------------------------------ EW[l] = E[l] @ W[l], stored transposed [c'][32]
// block = (l, j): thread c' computes sum_c E[l][j][c] * W[l][c][c']
__global__ __launch_bounds__(256) void ew_k(
    const float* __restrict__ edge_emb, const float* __restrict__ W,
    unsigned short* __restrict__ EWt)
{
  __shared__ float e[256];
  int l = blockIdx.x / 24, j = blockIdx.x % 24;
  int c = threadIdx.x;
  e[c] = edge_emb[(long)l * 6144 + j * 256 + c];
  __syncthreads();
  const float* Wl = W + (long)l * 65536;
  float acc = 0.f;
#pragma unroll 8
  for (int k = 0; k < 256; ++k) acc += e[k] * Wl[k * 256 + c];
  EWt[((long)l * 256 + c) * 32 + j] = f2h(acc);
}

// ---------------------------------------------------------------- aggregation
// XCD-sliced (slice = blockIdx%8 -> slab L2-resident per XCD). Wave = 8 nodes
// x 8 lanes (2 edge-groups x 4 chunks of 16B). Pure gather+add: histogram term
// folded into GEMM (K=288). Packed fp16 accumulate, single fp32 flush.
template<int FUSE_BN>
__device__ __forceinline__ hf8 bnval(const uint4 u, const hf8 scv, const hf8 shv)
{
  union { uint4 u4; hf8 h8; } cv;
  cv.u4 = u;
  hf8 y = cv.h8;
  if (FUSE_BN) {
    y = y * scv + shv;                        // v_pk_fma_f16 x4
    y = __builtin_elementwise_max(y, (hf8)0); // v_pk_max_f16 x4
  }
  return y;
}

template<int FUSE_BN>
__global__ __launch_bounds__(256) void aggregate_t(
    const unsigned short* __restrict__ tab_base,
    const int* __restrict__ csrc, const int* __restrict__ row_start,
    const unsigned short* __restrict__ sc16,
    const unsigned short* __restrict__ sh16,
    unsigned short* __restrict__ X16)
{
  int bid = blockIdx.x;
  int s = bid & 7;                               // slice == XCD (heuristic)
  int grp = bid >> 3;
  int lane = threadIdx.x & 63;
  int w = threadIdx.x >> 6;
  int nd = lane >> 3;            // node within wave (8)
  int g = (lane >> 2) & 1;       // edge group (2)
  int q = lane & 3;              // 16B chunk (4)
  int n = grp * 32 + w * 8 + nd; // 1563 grps * 32 = 50016 >= 50000
  if (n >= N_NODESC) return;
  const unsigned short* tab = tab_base + (long)s * SLAB;
  hf8 scv = (hf8)0, shv = (hf8)0;
  if (FUSE_BN) {
    scv = *(const hf8*)(sc16 + s * 32 + q * 8);
    shv = *(const hf8*)(sh16 + s * 32 + q * 8);
  }
  int s0 = row_start[n], s1 = row_start[n + 1];
  hf8 hacc = (hf8)0;                             // packed fp16 accumulator
  if (g == 0) {                                  // self row (once, pre-reduce)
    uint4 u = *(const uint4*)(tab + (long)n * 32 + q * 8);
    hacc = hacc + bnval<FUSE_BN>(u, scv, shv);
  }
  int e = s0 + g;
  for (; e + 2 < s1; e += 4) {                   // 2 edges in flight per lane
    int i0 = csrc[e];
    int i1 = csrc[e + 2];
    uint4 u0 = *(const uint4*)(tab + (long)i0 * 32 + q * 8);
    uint4 u1 = *(const uint4*)(tab + (long)i1 * 32 + q * 8);
    hacc = hacc + bnval<FUSE_BN>(u0, scv, shv);
    hacc = hacc + bnval<FUSE_BN>(u1, scv, shv);
  }
  if (e < s1) {
    int i0 = csrc[e];
    uint4 u = *(const uint4*)(tab + (long)i0 * 32 + q * 8);
    hacc = hacc + bnval<FUSE_BN>(u, scv, shv);
  }
  // fp32 flush, then reduce over the 2 edge-groups (lane bit 2)
  float a[8];
#pragma unroll
  for (int k = 0; k < 8; ++k) a[k] = (float)hacc[k];
#pragma unroll
  for (int k = 0; k < 8; ++k) a[k] += __shfl_xor(a[k], 4);
  if (g == 0) {                                  // 4 lanes/node write 64B
    float inv = 1.0f / (float)(s1 - s0 + 1);
    uint4 o;
    o.x = packh2(a[0] * inv, a[1] * inv);
    o.y = packh2(a[2] * inv, a[3] * inv);
    o.z = packh2(a[4] * inv, a[5] * inv);
    o.w = packh2(a[6] * inv, a[7] * inv);
    *(uint4*)(X16 + (long)s * SLAB + (long)n * 32 + q * 8) = o;
  }
}

// ---------------------------------------------------------------- MFMA GEMM fp16
// Y16 = fp16([X | cntf] @ [W ; EW] + b), K = 256 + 32(24 used).
// Slice-major X/Y; per-block BN partials (no atomics).
__global__ __launch_bounds__(256) void gemm_k(
    const unsigned short* __restrict__ X16, const unsigned short* __restrict__ Bt,
    const unsigned short* __restrict__ cntf, const unsigned short* __restrict__ EWt,
    const float* __restrict__ bl, unsigned short* __restrict__ Y16,
    float* __restrict__ Pp)
{
  __shared__ unsigned short As[128 * 72];
  __shared__ unsigned short Bs[128 * 72];
  __shared__ float red_s[256];
  __shared__ float red_q[256];

  int t = threadIdx.x;
  int bm = blockIdx.x, bn = blockIdx.y;
  int row0 = bm * 128, nc0 = bn * 128;
  int w = t >> 6, l = t & 63;
  int wr = w >> 1, wc = w & 1;
  int lr = l & 15, lk = l >> 4;

  fx4 acc[4][4];
#pragma unroll
  for (int i = 0; i < 4; ++i)
#pragma unroll
    for (int j = 0; j < 4; ++j) acc[i][j] = (fx4){0.f, 0.f, 0.f, 0.f};

  for (int kb = 0; kb < 5; ++kb) {
    __syncthreads();
    if (kb < 4) {
      int kc = kb * 64;
#pragma unroll
      for (int q = 0; q < 2; ++q) {
        int id = q * 256 + t;
        int r = id >> 2, c16 = (id & 3) << 4;
        int ktot = kc + c16;
        long gA = (long)(ktot >> 5) * SLAB + (long)(row0 + r) * 32 + (ktot & 31);
        long gB = (long)(nc0 + r) * 256 + ktot;
        *(uint4*)&As[r * 72 + c16] = *(const uint4*)(X16 + gA);
        *(uint4*)&As[r * 72 + c16 + 8] = *(const uint4*)(X16 + gA + 8);
        *(uint4*)&Bs[r * 72 + c16] = *(const uint4*)(Bt + gB);
        *(uint4*)&Bs[r * 72 + c16 + 8] = *(const uint4*)(Bt + gB + 8);
      }
    } else {
#pragma unroll
      for (int q = 0; q < 2; ++q) {
        int id = q * 256 + t;
        int r = id >> 2, c8 = (id & 3) << 3;
        *(uint4*)&As[r * 72 + c8] = *(const uint4*)(cntf + (long)(row0 + r) * 32 + c8);
        *(uint4*)&Bs[r * 72 + c8] = *(const uint4*)(EWt + (long)(nc0 + r) * 32 + c8);
      }
    }
    __syncthreads();
    int nks = (kb < 4) ? 2 : 1;
    for (int ks = 0; ks < nks; ++ks) {
      int ko = ks * 32 + lk * 8;
      hf8 af[4], bf[4];
#pragma unroll
      for (int f = 0; f < 4; ++f) {
        af[f] = *(const hf8*)&As[(wr * 64 + f * 16 + lr) * 72 + ko];
        bf[f] = *(const hf8*)&Bs[(wc * 64 + f * 16 + lr) * 72 + ko];
      }
#pragma unroll
      for (int fm = 0; fm < 4; ++fm)
#pragma unroll
        for (int fn = 0; fn < 4; ++fn)
          acc[fm][fn] = __builtin_amdgcn_mfma_f32_16x16x32_f16(
              af[fm], bf[fn], acc[fm][fn], 0, 0, 0);
    }
  }

  float bcol[4];
#pragma unroll
  for (int fn = 0; fn < 4; ++fn) bcol[fn] = bl[nc0 + wc * 64 + fn * 16 + lr];
  float sp[4] = {0.f, 0.f, 0.f, 0.f}, qp[4] = {0.f, 0.f, 0.f, 0.f};
#pragma unroll
  for (int fm = 0; fm < 4; ++fm)
#pragma unroll
    for (int fn = 0; fn < 4; ++fn) {
      int cl = wc * 64 + fn * 16 + lr;
      int col = nc0 + cl;
      long ybase = (long)(col >> 5) * SLAB + (col & 31);
#pragma unroll
      for (int j = 0; j < 4; ++j) {
        int rl = wr * 64 + fm * 16 + lk * 4 + j;
        float v = acc[fm][fn][j] + bcol[fn];
        Y16[ybase + (long)(row0 + rl) * 32] = f2h(v);
        sp[fn] += v; qp[fn] += v * v;
      }
    }
#pragma unroll
  for (int fn = 0; fn < 4; ++fn) {
    sp[fn] += __shfl_xor(sp[fn], 16);
    sp[fn] += __shfl_xor(sp[fn], 32);
    qp[fn] += __shfl_xor(qp[fn], 16);
    qp[fn] += __shfl_xor(qp[fn], 32);
  }
  if (lk == 0) {
#pragma unroll
    for (int fn = 0; fn < 4; ++fn) {
      red_s[w * 64 + fn * 16 + lr] = sp[fn];
      red_q[w * 64 + fn * 16 + lr] = qp[fn];
    }
  }
  __syncthreads();
  if (t < 128) {
    float s = red_s[t] + red_s[128 + t];
    float q = red_q[t] + red_q[128 + t];
    float* p = Pp + (bm * 2 + bn) * 256;
    p[t] = s;
    p[128 + t] = q;
  }
}

// --------------------------- BN stats reduce + finalize (256 blocks, parallel)
__global__ __launch_bounds__(128) void stats_finalize_k(
    const float* __restrict__ Pp, const float* __restrict__ bl,
    const float* __restrict__ gamma, const float* __restrict__ beta,
    float* __restrict__ scale, float* __restrict__ shiftv,
    unsigned short* __restrict__ sc16, unsigned short* __restrict__ sh16)
{
  __shared__ float red_s[128];
  __shared__ float red_q[128];
  int c = blockIdx.x;                 // one column per block
  int half = c >> 7, cl = c & 127;
  int t = threadIdx.x;
  float s = 0.f, q = 0.f;
  for (int bm = t; bm < MTILES; bm += 128) {
    const float* p = Pp + (bm * 2 + half) * 256;
    s += p[cl];
    q += p[128 + cl];
  }
  red_s[t] = s; red_q[t] = q;
  __syncthreads();
#pragma unroll
  for (int off = 64; off > 0; off >>= 1) {
    if (t < off) {
      red_s[t] += red_s[t + off];
      red_q[t] += red_q[t + off];
    }
    __syncthreads();
  }
  if (t == 0) {
    s = red_s[0]; q = red_q[0];
    float bc = bl[c];
    s -= (float)(N_PAD - N_NODESC) * bc;
    q -= (float)(N_PAD - N_NODESC) * bc * bc;
    const float invN = 1.0f / (float)N_NODESC;
    float mu = s * invN;
    float var = q * invN - mu * mu;
    float rsq = rsqrtf(var + 1e-5f);
    float sc = gamma[c] * rsq;
    float sh = beta[c] - mu * sc;
    scale[c] = sc;
    shiftv[c] = sh;
    sc16[c] = f2h(sc);
    sh16[c] = f2h(sh);
  }
}

// ---------------------------------------------------------------- mean pooling
__device__ __forceinline__ int lower_bound_g(const int* gid, int n, int g)
{
  int lo = 0, hi = n;
  while (lo < hi) {
    int mid = (lo + hi) >> 1;
    if (gid[mid] < g) lo = mid + 1; else hi = mid;
  }
  return lo;
}

// 1 block/graph, 8 waves stride rows; BN+relu inline (layer-4 params);
// slice-major Y16.
__global__ __launch_bounds__(512) void pool_k(
    const unsigned short* __restrict__ Y16, const int* __restrict__ gid,
    const float* __restrict__ scale, const float* __restrict__ shiftv,
    float* __restrict__ gpool)
{
  __shared__ float red[8 * 256];
  int g = blockIdx.x;
  int lo = lower_bound_g(gid, N_NODESC, g);
  int hi = lower_bound_g(gid, N_NODESC, g + 1);
  int t = threadIdx.x;
  int w = t >> 6, lane = t & 63;
  int col = lane * 4;
  long ybase = (long)(col >> 5) * SLAB + (col & 31);
  float4 sc = *(const float4*)(scale + col);
  float4 sh = *(const float4*)(shiftv + col);
  float a0 = 0.f, a1 = 0.f, a2 = 0.f, a3 = 0.f;
  for (int r = lo + w; r < hi; r += 8) {
    ushort4 u = *(const ushort4*)(Y16 + ybase + (long)r * 32);
    a0 += fmaxf(0.f, h2f(u.x) * sc.x + sh.x);
    a1 += fmaxf(0.f, h2f(u.y) * sc.y + sh.y);
    a2 += fmaxf(0.f, h2f(u.z) * sc.z + sh.z);
    a3 += fmaxf(0.f, h2f(u.w) * sc.w + sh.w);
  }
  *(float4*)&red[w * 256 + col] = make_float4(a0, a1, a2, a3);
  __syncthreads();
  if (t < 256) {
    float s = 0.f;
#pragma unroll
    for (int j = 0; j < 8; ++j) s += red[j * 256 + t];
    int c = hi - lo;
    gpool[g * 256 + t] = s / (float)(c > 0 ? c : 1);
  }
}

// ---------------------------------------------------------------- final proj
__global__ __launch_bounds__(128) void final_k(
    const float* __restrict__ gpool, const float* __restrict__ Wp,
    const float* __restrict__ bp, float* __restrict__ out)
{
  __shared__ float gr[256];
  int g = blockIdx.x, t = threadIdx.x;
  gr[t] = gpool[g * 256 + t];
  gr[t + 128] = gpool[g * 256 + t + 128];
  __syncthreads();
  float acc = bp[t];
#pragma unroll 8
  for (int k = 0; k < 256; ++k) acc += gr[k] * Wp[k * 128 + t];
  out[g * 128 + t] = acc;
}

// ---------------------------------------------------------------- launcher
extern "C" void kernel_launch(void* const* d_in, const int* in_sizes, int n_in,
                              void* d_out, int out_size, void* d_ws, size_t ws_size,
                              hipStream_t stream)
{
  (void)in_sizes; (void)n_in; (void)out_size; (void)ws_size;
  const int* nfeat = (const int*)d_in[0];
  const int* efeat = (const int*)d_in[1];
  const int* src = (const int*)d_in[2];
  const int* dst = (const int*)d_in[3];
  const int* gid = (const int*)d_in[4];
  const float* atom_emb = (const float*)d_in[5];
  const float* edge_emb = (const float*)d_in[6];
  const float* W = (const float*)d_in[7];
  const float* b = (const float*)d_in[8];
  const float* gamma = (const float*)d_in[9];
  const float* beta = (const float*)d_in[10];
  const float* Wp = (const float*)d_in[11];
  const float* bp = (const float*)d_in[12];
  float* out = (float*)d_out;

  char* ws = (char*)d_ws;
  unsigned short* h16 = (unsigned short*)ws; ws += (size_t)N_PAD * 512;
  unsigned short* Y16 = (unsigned short*)ws; ws += (size_t)N_PAD * 512;
  unsigned short* X16 = (unsigned short*)ws; ws += (size_t)N_PAD * 512;
  unsigned short* Wt = (unsigned short*)ws; ws += 5 * 65536 * 2;
  unsigned short* EWt = (unsigned short*)ws; ws += 5 * 256 * 32 * 2;
  unsigned short* cntf = (unsigned short*)ws; ws += (size_t)N_PAD * 32 * 2;
  int* csrc = (int*)ws; ws += 3200000;
  int* ceid = (int*)ws; ws += 3200000;
  int* row_start = (int*)ws; ws += 200064;
  int* degs_i = (int*)ws; ws += 200064;
  int* fill = (int*)ws; ws += 200064;
  float* Pp = (float*)ws; ws += MTILES * 2 * 256 * 4;
  float* scale = (float*)ws; ws += 1024;
  float* shiftv = (float*)ws; ws += 1024;
  unsigned short* sc16 = (unsigned short*)ws; ws += 512;
  unsigned short* sh16 = (unsigned short*)ws; ws += 512;
  float* gpool = (float*)ws; ws += 131072;

  hipMemsetAsync(degs_i, 0, 200000, stream);
  hipMemsetAsync(fill, 0, 200000, stream);
  // zero X16 pad rows in each slice slab so GEMM pad output is exactly b[c]
  for (int s = 0; s < 8; ++s)
    hipMemsetAsync(X16 + (size_t)s * SLAB + (size_t)N_NODESC * 32, 0,
                   (size_t)(N_PAD - N_NODESC) * 64, stream);

  wprep_k<<<1280, 256, 0, stream>>>(W, Wt);
  ew_k<<<120, 256, 0, stream>>>(edge_emb, W, EWt);
  atom_encode_k<<<12500, 256, 0, stream>>>(nfeat, atom_emb, h16);
  deg_k<<<3125, 256, 0, stream>>>(dst, degs_i);
  scan_k<<<1, 1024, 0, stream>>>(degs_i, row_start, N_NODESC);
  scatter_k<<<3125, 256, 0, stream>>>(src, dst, row_start, fill, csrc, ceid);
  cntf_k<<<196, 256, 0, stream>>>(ceid, row_start, efeat, cntf);

  // layer 0 aggregate: atom-encoded h16, no BN
  aggregate_t<0><<<12504, 256, 0, stream>>>(h16, csrc, row_start,
                                            nullptr, nullptr, X16);
  for (int l = 0; l < 5; ++l) {
    gemm_k<<<dim3(MTILES, 2), 256, 0, stream>>>(X16, Wt + l * 65536, cntf,
                                                EWt + l * 8192, b + l * 256,
                                                Y16, Pp);
    stats_finalize_k<<<256, 128, 0, stream>>>(Pp, b + l * 256, gamma + l * 256,
                                              beta + l * 256, scale, shiftv,
                                              sc16, sh16);
    if (l < 4)
      aggregate_t<1><<<12504, 256, 0, stream>>>(Y16, csrc, row_start,
                                                sc16, sh16, X16);
  }

  pool_k<<<128, 512, 0, stream>>>(Y16, gid, scale, shiftv, gpool);
  final_k<<<128, 128, 0, stream>>>(gpool, Wp, bp, out);
}

// Round 16
// 612.410 us; speedup vs baseline: 3.4515x; 1.0474x over previous
//
#include <hip/hip_runtime.h>

#define N_NODESC 50000
#define N_PAD 50176          // 392 * 128
#define N_EDGESC 800000
#define N_GRAPHSC 128
#define EMBEDC 256
#define MTILES 392
#define SLAB ((long)N_PAD * 32)   // halves per 32-col slice slab

typedef __attribute__((ext_vector_type(8))) _Float16 hf8;
typedef __attribute__((ext_vector_type(4))) float fx4;

__device__ __forceinline__ float h2f(unsigned short u) {
  _Float16 h = *(_Float16*)&u;
  return (float)h;
}
__device__ __forceinline__ unsigned short f2h(float f) {
  _Float16 h = (_Float16)f;
  return *(unsigned short*)&h;
}
__device__ __forceinline__ unsigned int packh2(float lo, float hi) {
  return (unsigned int)f2h(lo) | ((unsigned int)f2h(hi) << 16);
}

// ------------------------------------------- atom encoder (slice-major h16)
__global__ __launch_bounds__(256) void atom_encode_k(
    const int* __restrict__ nfeat, const float* __restrict__ atom_emb,
    unsigned short* __restrict__ h16)
{
  int w = threadIdx.x >> 6, lane = threadIdx.x & 63;
  int n = blockIdx.x * 4 + w;
  if (n >= N_NODESC) return;
  const int* nf = nfeat + n * 9;
  float ax = 0.f, ay = 0.f, az = 0.f, aw = 0.f;
#pragma unroll
  for (int c = 0; c < 9; ++c) {
    int idx = nf[c];
    const float4* row = (const float4*)(atom_emb + (c * 128 + idx) * EMBEDC);
    float4 v = row[lane];
    ax += v.x; ay += v.y; az += v.z; aw += v.w;
  }
  ushort4 o;
  o.x = f2h(ax); o.y = f2h(ay); o.z = f2h(az); o.w = f2h(aw);
  int col = lane * 4;
  *(ushort4*)(h16 + (long)(col >> 5) * SLAB + (long)n * 32 + (col & 31)) = o;
}

// ---------------------------------------------------------------- degree count
__global__ __launch_bounds__(256) void deg_k(
    const int* __restrict__ dst, int* __restrict__ degs)
{
  int e = blockIdx.x * 256 + threadIdx.x;
  if (e >= N_EDGESC) return;
  atomicAdd(&degs[dst[e]], 1);
}

// ------------------------------------------- parallel 3-phase exclusive scan
// phase 1: per-block (1024 elems) sums
__global__ __launch_bounds__(256) void scan_partial_k(
    const int* __restrict__ deg, int* __restrict__ bsum)
{
  __shared__ int buf[256];
  int b = blockIdx.x, t = threadIdx.x;
  int idx0 = b * 1024 + t * 4;
  int s = 0;
#pragma unroll
  for (int i = 0; i < 4; ++i) {
    int idx = idx0 + i;
    if (idx < N_NODESC) s += deg[idx];
  }
  buf[t] = s;
  __syncthreads();
  for (int off = 1; off < 256; off <<= 1) {
    int add = (t >= off) ? buf[t - off] : 0;
    __syncthreads();
    buf[t] += add;
    __syncthreads();
  }
  if (t == 255) bsum[b] = buf[255];
}
// phase 2: exclusive scan of the 49 block sums (+ total at [49])
__global__ __launch_bounds__(64) void scan_sums_k(
    const int* __restrict__ bsum, int* __restrict__ boff)
{
  __shared__ int buf[64];
  int t = threadIdx.x;
  int v = (t < 49) ? bsum[t] : 0;
  buf[t] = v;
  __syncthreads();
  for (int off = 1; off < 64; off <<= 1) {
    int add = (t >= off) ? buf[t - off] : 0;
    __syncthreads();
    buf[t] += add;
    __syncthreads();
  }
  if (t < 49) boff[t] = buf[t] - v;   // exclusive
  if (t == 48) boff[49] = buf[48];    // total
}
// phase 3: block-local exclusive scan + block offset
__global__ __launch_bounds__(256) void scan_final_k(
    const int* __restrict__ deg, const int* __restrict__ boff,
    int* __restrict__ row_start)
{
  __shared__ int buf[256];
  int b = blockIdx.x, t = threadIdx.x;
  int idx0 = b * 1024 + t * 4;
  int loc[4];
  int s = 0;
#pragma unroll
  for (int i = 0; i < 4; ++i) {
    int idx = idx0 + i;
    int v = (idx < N_NODESC) ? deg[idx] : 0;
    loc[i] = v; s += v;
  }
  buf[t] = s;
  __syncthreads();
  for (int off = 1; off < 256; off <<= 1) {
    int add = (t >= off) ? buf[t - off] : 0;
    __syncthreads();
    buf[t] += add;
    __syncthreads();
  }
  int run = boff[b] + buf[t] - s;
#pragma unroll
  for (int i = 0; i < 4; ++i) {
    int idx = idx0 + i;
    if (idx < N_NODESC) row_start[idx] = run;
    run += loc[i];
  }
  if (b == 48 && t == 255) row_start[N_NODESC] = boff[49];
}

// ---------------------------------------------------------------- CSR scatter
// packed (src, eid) int2: one cache line per edge instead of two
__global__ __launch_bounds__(256) void scatter_k(
    const int* __restrict__ src, const int* __restrict__ dst,
    const int* __restrict__ row_start, int* __restrict__ fill,
    int2* __restrict__ csr2)
{
  int e = blockIdx.x * 256 + threadIdx.x;
  if (e >= N_EDGESC) return;
  int d = dst[e];
  int pos = row_start[d] + atomicAdd(&fill[d], 1);
  csr2[pos] = make_int2(src[e], e);
}

// ------------------- per-node edge-feature histogram -> fp16 cnt/(deg+1)
__global__ __launch_bounds__(256) void cntf_k(
    const int2* __restrict__ csr2, const int* __restrict__ row_start,
    const int* __restrict__ efeat, unsigned short* __restrict__ cntf)
{
  __shared__ int lc[256 * 25];
  int t = threadIdx.x;
  int n = blockIdx.x * 256 + t;          // 196*256 == 50176 == N_PAD
  int base = t * 25;
#pragma unroll
  for (int j = 0; j < 24; ++j) lc[base + j] = 0;
  float inv = 0.f;
  if (n < N_NODESC) {
    int s0 = row_start[n], s1 = row_start[n + 1];
    inv = 1.0f / (float)(s1 - s0 + 1);
    for (int e = s0; e < s1; ++e) {
      int eid = csr2[e].y;
      int v0 = efeat[eid * 3 + 0];
      int v1 = efeat[eid * 3 + 1];
      int v2 = efeat[eid * 3 + 2];
      lc[base + v0]++;
      lc[base + 8 + v1]++;
      lc[base + 16 + v2]++;
    }
  }
  unsigned int* o = (unsigned int*)(cntf + (long)n * 32);
#pragma unroll
  for (int j = 0; j < 12; ++j)
    o[j] = packh2((float)lc[base + 2 * j] * inv, (float)lc[base + 2 * j + 1] * inv);
#pragma unroll
  for (int j = 12; j < 16; ++j) o[j] = 0u;
}

// ------------------------------------------------ W transpose + fp16 convert
__global__ __launch_bounds__(256) void wprep_k(
    const float* __restrict__ W, unsigned short* __restrict__ Wt)
{
  int tid = blockIdx.x * 256 + threadIdx.x;     // 5*65536
  int l = tid >> 16, r = tid & 65535;
  int n = r >> 8, k = r & 255;
  float w = W[(long)l * 65536 + k * 256 + n];
  Wt[tid] = f2h(w);                             // tid == l*65536 + n*256 + k
}

// ------------------------------ EW[l] = E[l] @ W[l], stored transposed [c'][32]
__global__ __launch_bounds__(256) void ew_k(
    const float* __restrict__ edge_emb, const float* __restrict__ W,
    unsigned short* __restrict__ EWt)
{
  __shared__ float e[256];
  int l = blockIdx.x / 24, j = blockIdx.x % 24;
  int c = threadIdx.x;
  e[c] = edge_emb[(long)l * 6144 + j * 256 + c];
  __syncthreads();
  const float* Wl = W + (long)l * 65536;
  float acc = 0.f;
#pragma unroll 8
  for (int k = 0; k < 256; ++k) acc += e[k] * Wl[k * 256 + c];
  EWt[((long)l * 256 + c) * 32 + j] = f2h(acc);
}

// ---------------------------------------------------------------- aggregation
// XCD-sliced (slice = blockIdx%8 -> slab L2-resident per XCD). Wave = 8 nodes
// x 8 lanes (2 edge-groups x 4 chunks of 16B). Pure gather+add: histogram term
// folded into GEMM (K=288). Packed fp16 accumulate, single fp32 flush.
template<int FUSE_BN>
__device__ __forceinline__ hf8 bnval(const uint4 u, const hf8 scv, const hf8 shv)
{
  union { uint4 u4; hf8 h8; } cv;
  cv.u4 = u;
  hf8 y = cv.h8;
  if (FUSE_BN) {
    y = y * scv + shv;                        // v_pk_fma_f16 x4
    y = __builtin_elementwise_max(y, (hf8)0); // v_pk_max_f16 x4
  }
  return y;
}

template<int FUSE_BN>
__global__ __launch_bounds__(256) void aggregate_t(
    const unsigned short* __restrict__ tab_base,
    const int2* __restrict__ csr2, const int* __restrict__ row_start,
    const unsigned short* __restrict__ sc16,
    const unsigned short* __restrict__ sh16,
    unsigned short* __restrict__ X16)
{
  int bid = blockIdx.x;
  int s = bid & 7;                               // slice == XCD (heuristic)
  int grp = bid >> 3;
  int lane = threadIdx.x & 63;
  int w = threadIdx.x >> 6;
  int nd = lane >> 3;            // node within wave (8)
  int g = (lane >> 2) & 1;       // edge group (2)
  int q = lane & 3;              // 16B chunk (4)
  int n = grp * 32 + w * 8 + nd; // 1563 grps * 32 = 50016 >= 50000
  if (n >= N_NODESC) return;
  const unsigned short* tab = tab_base + (long)s * SLAB;
  hf8 scv = (hf8)0, shv = (hf8)0;
  if (FUSE_BN) {
    scv = *(const hf8*)(sc16 + s * 32 + q * 8);
    shv = *(const hf8*)(sh16 + s * 32 + q * 8);
  }
  int s0 = row_start[n], s1 = row_start[n + 1];
  hf8 hacc = (hf8)0;                             // packed fp16 accumulator
  if (g == 0) {                                  // self row (once, pre-reduce)
    uint4 u = *(const uint4*)(tab + (long)n * 32 + q * 8);
    hacc = hacc + bnval<FUSE_BN>(u, scv, shv);
  }
  int e = s0 + g;
  for (; e + 2 < s1; e += 4) {                   // 2 edges in flight per lane
    int i0 = csr2[e].x;
    int i1 = csr2[e + 2].x;
    uint4 u0 = *(const uint4*)(tab + (long)i0 * 32 + q * 8);
    uint4 u1 = *(const uint4*)(tab + (long)i1 * 32 + q * 8);
    hacc = hacc + bnval<FUSE_BN>(u0, scv, shv);
    hacc = hacc + bnval<FUSE_BN>(u1, scv, shv);
  }
  if (e < s1) {
    int i0 = csr2[e].x;
    uint4 u = *(const uint4*)(tab + (long)i0 * 32 + q * 8);
    hacc = hacc + bnval<FUSE_BN>(u, scv, shv);
  }
  // fp32 flush, then reduce over the 2 edge-groups (lane bit 2)
  float a[8];
#pragma unroll
  for (int k = 0; k < 8; ++k) a[k] = (float)hacc[k];
#pragma unroll
  for (int k = 0; k < 8; ++k) a[k] += __shfl_xor(a[k], 4);
  if (g == 0) {                                  // 4 lanes/node write 64B
    float inv = 1.0f / (float)(s1 - s0 + 1);
    uint4 o;
    o.x = packh2(a[0] * inv, a[1] * inv);
    o.y = packh2(a[2] * inv, a[3] * inv);
    o.z = packh2(a[4] * inv, a[5] * inv);
    o.w = packh2(a[6] * inv, a[7] * inv);
    *(uint4*)(X16 + (long)s * SLAB + (long)n * 32 + q * 8) = o;
  }
}

// ---------------------------------------------------------------- MFMA GEMM fp16
// Y16 = fp16([X | cntf] @ [W ; EW] + b), K = 256 + 32(24 used).
__global__ __launch_bounds__(256) void gemm_k(
    const unsigned short* __restrict__ X16, const unsigned short* __restrict__ Bt,
    const unsigned short* __restrict__ cntf, const unsigned short* __restrict__ EWt,
    const float* __restrict__ bl, unsigned short* __restrict__ Y16,
    float* __restrict__ Pp)
{
  __shared__ unsigned short As[128 * 72];
  __shared__ unsigned short Bs[128 * 72];
  __shared__ float red_s[256];
  __shared__ float red_q[256];

  int t = threadIdx.x;
  int bm = blockIdx.x, bn = blockIdx.y;
  int row0 = bm * 128, nc0 = bn * 128;
  int w = t >> 6, l = t & 63;
  int wr = w >> 1, wc = w & 1;
  int lr = l & 15, lk = l >> 4;

  fx4 acc[4][4];
#pragma unroll
  for (int i = 0; i < 4; ++i)
#pragma unroll
    for (int j = 0; j < 4; ++j) acc[i][j] = (fx4){0.f, 0.f, 0.f, 0.f};

  for (int kb = 0; kb < 5; ++kb) {
    __syncthreads();
    if (kb < 4) {
      int kc = kb * 64;
#pragma unroll
      for (int q = 0; q < 2; ++q) {
        int id = q * 256 + t;
        int r = id >> 2, c16 = (id & 3) << 4;
        int ktot = kc + c16;
        long gA = (long)(ktot >> 5) * SLAB + (long)(row0 + r) * 32 + (ktot & 31);
        long gB = (long)(nc0 + r) * 256 + ktot;
        *(uint4*)&As[r * 72 + c16] = *(const uint4*)(X16 + gA);
        *(uint4*)&As[r * 72 + c16 + 8] = *(const uint4*)(X16 + gA + 8);
        *(uint4*)&Bs[r * 72 + c16] = *(const uint4*)(Bt + gB);
        *(uint4*)&Bs[r * 72 + c16 + 8] = *(const uint4*)(Bt + gB + 8);
      }
    } else {
#pragma unroll
      for (int q = 0; q < 2; ++q) {
        int id = q * 256 + t;
        int r = id >> 2, c8 = (id & 3) << 3;
        *(uint4*)&As[r * 72 + c8] = *(const uint4*)(cntf + (long)(row0 + r) * 32 + c8);
        *(uint4*)&Bs[r * 72 + c8] = *(const uint4*)(EWt + (long)(nc0 + r) * 32 + c8);
      }
    }
    __syncthreads();
    int nks = (kb < 4) ? 2 : 1;
    for (int ks = 0; ks < nks; ++ks) {
      int ko = ks * 32 + lk * 8;
      hf8 af[4], bf[4];
#pragma unroll
      for (int f = 0; f < 4; ++f) {
        af[f] = *(const hf8*)&As[(wr * 64 + f * 16 + lr) * 72 + ko];
        bf[f] = *(const hf8*)&Bs[(wc * 64 + f * 16 + lr) * 72 + ko];
      }
#pragma unroll
      for (int fm = 0; fm < 4; ++fm)
#pragma unroll
        for (int fn = 0; fn < 4; ++fn)
          acc[fm][fn] = __builtin_amdgcn_mfma_f32_16x16x32_f16(
              af[fm], bf[fn], acc[fm][fn], 0, 0, 0);
    }
  }

  float bcol[4];
#pragma unroll
  for (int fn = 0; fn < 4; ++fn) bcol[fn] = bl[nc0 + wc * 64 + fn * 16 + lr];
  float sp[4] = {0.f, 0.f, 0.f, 0.f}, qp[4] = {0.f, 0.f, 0.f, 0.f};
#pragma unroll
  for (int fm = 0; fm < 4; ++fm)
#pragma unroll
    for (int fn = 0; fn < 4; ++fn) {
      int cl = wc * 64 + fn * 16 + lr;
      int col = nc0 + cl;
      long ybase = (long)(col >> 5) * SLAB + (col & 31);
#pragma unroll
      for (int j = 0; j < 4; ++j) {
        int rl = wr * 64 + fm * 16 + lk * 4 + j;
        float v = acc[fm][fn][j] + bcol[fn];
        Y16[ybase + (long)(row0 + rl) * 32] = f2h(v);
        sp[fn] += v; qp[fn] += v * v;
      }
    }
#pragma unroll
  for (int fn = 0; fn < 4; ++fn) {
    sp[fn] += __shfl_xor(sp[fn], 16);
    sp[fn] += __shfl_xor(sp[fn], 32);
    qp[fn] += __shfl_xor(qp[fn], 16);
    qp[fn] += __shfl_xor(qp[fn], 32);
  }
  if (lk == 0) {
#pragma unroll
    for (int fn = 0; fn < 4; ++fn) {
      red_s[w * 64 + fn * 16 + lr] = sp[fn];
      red_q[w * 64 + fn * 16 + lr] = qp[fn];
    }
  }
  __syncthreads();
  if (t < 128) {
    float s = red_s[t] + red_s[128 + t];
    float q = red_q[t] + red_q[128 + t];
    float* p = Pp + (bm * 2 + bn) * 256;
    p[t] = s;
    p[128 + t] = q;
  }
}

// --------------------------- BN stats reduce + finalize (256 blocks, parallel)
__global__ __launch_bounds__(128) void stats_finalize_k(
    const float* __restrict__ Pp, const float* __restrict__ bl,
    const float* __restrict__ gamma, const float* __restrict__ beta,
    float* __restrict__ scale, float* __restrict__ shiftv,
    unsigned short* __restrict__ sc16, unsigned short* __restrict__ sh16)
{
  __shared__ float red_s[128];
  __shared__ float red_q[128];
  int c = blockIdx.x;                 // one column per block
  int half = c >> 7, cl = c & 127;
  int t = threadIdx.x;
  float s = 0.f, q = 0.f;
  for (int bm = t; bm < MTILES; bm += 128) {
    const float* p = Pp + (bm * 2 + half) * 256;
    s += p[cl];
    q += p[128 + cl];
  }
  red_s[t] = s; red_q[t] = q;
  __syncthreads();
#pragma unroll
  for (int off = 64; off > 0; off >>= 1) {
    if (t < off) {
      red_s[t] += red_s[t + off];
      red_q[t] += red_q[t + off];
    }
    __syncthreads();
  }
  if (t == 0) {
    s = red_s[0]; q = red_q[0];
    float bc = bl[c];
    s -= (float)(N_PAD - N_NODESC) * bc;
    q -= (float)(N_PAD - N_NODESC) * bc * bc;
    const float invN = 1.0f / (float)N_NODESC;
    float mu = s * invN;
    float var = q * invN - mu * mu;
    float rsq = rsqrtf(var + 1e-5f);
    float sc = gamma[c] * rsq;
    float sh = beta[c] - mu * sc;
    scale[c] = sc;
    shiftv[c] = sh;
    sc16[c] = f2h(sc);
    sh16[c] = f2h(sh);
  }
}

// ---------------------------------------------------------------- mean pooling
__device__ __forceinline__ int lower_bound_g(const int* gid, int n, int g)
{
  int lo = 0, hi = n;
  while (lo < hi) {
    int mid = (lo + hi) >> 1;
    if (gid[mid] < g) lo = mid + 1; else hi = mid;
  }
  return lo;
}

__global__ __launch_bounds__(512) void pool_k(
    const unsigned short* __restrict__ Y16, const int* __restrict__ gid,
    const float* __restrict__ scale, const float* __restrict__ shiftv,
    float* __restrict__ gpool)
{
  __shared__ float red[8 * 256];
  int g = blockIdx.x;
  int lo = lower_bound_g(gid, N_NODESC, g);
  int hi = lower_bound_g(gid, N_NODESC, g + 1);
  int t = threadIdx.x;
  int w = t >> 6, lane = t & 63;
  int col = lane * 4;
  long ybase = (long)(col >> 5) * SLAB + (col & 31);
  float4 sc = *(const float4*)(scale + col);
  float4 sh = *(const float4*)(shiftv + col);
  float a0 = 0.f, a1 = 0.f, a2 = 0.f, a3 = 0.f;
  for (int r = lo + w; r < hi; r += 8) {
    ushort4 u = *(const ushort4*)(Y16 + ybase + (long)r * 32);
    a0 += fmaxf(0.f, h2f(u.x) * sc.x + sh.x);
    a1 += fmaxf(0.f, h2f(u.y) * sc.y + sh.y);
    a2 += fmaxf(0.f, h2f(u.z) * sc.z + sh.z);
    a3 += fmaxf(0.f, h2f(u.w) * sc.w + sh.w);
  }
  *(float4*)&red[w * 256 + col] = make_float4(a0, a1, a2, a3);
  __syncthreads();
  if (t < 256) {
    float s = 0.f;
#pragma unroll
    for (int j = 0; j < 8; ++j) s += red[j * 256 + t];
    int c = hi - lo;
    gpool[g * 256 + t] = s / (float)(c > 0 ? c : 1);
  }
}

// ---------------------------------------------------------------- final proj
__global__ __launch_bounds__(128) void final_k(
    const float* __restrict__ gpool, const float* __restrict__ Wp,
    const float* __restrict__ bp, float* __restrict__ out)
{
  __shared__ float gr[256];
  int g = blockIdx.x, t = threadIdx.x;
  gr[t] = gpool[g * 256 + t];
  gr[t + 128] = gpool[g * 256 + t + 128];
  __syncthreads();
  float acc = bp[t];
#pragma unroll 8
  for (int k = 0; k < 256; ++k) acc += gr[k] * Wp[k * 128 + t];
  out[g * 128 + t] = acc;
}

// ---------------------------------------------------------------- launcher
extern "C" void kernel_launch(void* const* d_in, const int* in_sizes, int n_in,
                              void* d_out, int out_size, void* d_ws, size_t ws_size,
                              hipStream_t stream)
{
  (void)in_sizes; (void)n_in; (void)out_size; (void)ws_size;
  const int* nfeat = (const int*)d_in[0];
  const int* efeat = (const int*)d_in[1];
  const int* src = (const int*)d_in[2];
  const int* dst = (const int*)d_in[3];
  const int* gid = (const int*)d_in[4];
  const float* atom_emb = (const float*)d_in[5];
  const float* edge_emb = (const float*)d_in[6];
  const float* W = (const float*)d_in[7];
  const float* b = (const float*)d_in[8];
  const float* gamma = (const float*)d_in[9];
  const float* beta = (const float*)d_in[10];
  const float* Wp = (const float*)d_in[11];
  const float* bp = (const float*)d_in[12];
  float* out = (float*)d_out;

  char* ws = (char*)d_ws;
  unsigned short* h16 = (unsigned short*)ws; ws += (size_t)N_PAD * 512;
  unsigned short* Y16 = (unsigned short*)ws; ws += (size_t)N_PAD * 512;
  unsigned short* X16 = (unsigned short*)ws; ws += (size_t)N_PAD * 512;
  unsigned short* Wt = (unsigned short*)ws; ws += 5 * 65536 * 2;
  unsigned short* EWt = (unsigned short*)ws; ws += 5 * 256 * 32 * 2;
  unsigned short* cntf = (unsigned short*)ws; ws += (size_t)N_PAD * 32 * 2;
  int2* csr2 = (int2*)ws; ws += 6400000;
  int* row_start = (int*)ws; ws += 200064;
  int* degs_i = (int*)ws; ws += 200064;
  int* fill = (int*)ws; ws += 200064;
  int* bsum = (int*)ws; ws += 256;
  int* boff = (int*)ws; ws += 256;
  float* Pp = (float*)ws; ws += MTILES * 2 * 256 * 4;
  float* scale = (float*)ws; ws += 1024;
  float* shiftv = (float*)ws; ws += 1024;
  unsigned short* sc16 = (unsigned short*)ws; ws += 512;
  unsigned short* sh16 = (unsigned short*)ws; ws += 512;
  float* gpool = (float*)ws; ws += 131072;

  hipMemsetAsync(degs_i, 0, 200000, stream);
  hipMemsetAsync(fill, 0, 200000, stream);
  // zero X16 pad rows in each slice slab so GEMM pad output is exactly b[c]
  for (int s = 0; s < 8; ++s)
    hipMemsetAsync(X16 + (size_t)s * SLAB + (size_t)N_NODESC * 32, 0,
                   (size_t)(N_PAD - N_NODESC) * 64, stream);

  wprep_k<<<1280, 256, 0, stream>>>(W, Wt);
  ew_k<<<120, 256, 0, stream>>>(edge_emb, W, EWt);
  atom_encode_k<<<12500, 256, 0, stream>>>(nfeat, atom_emb, h16);
  deg_k<<<3125, 256, 0, stream>>>(dst, degs_i);
  scan_partial_k<<<49, 256, 0, stream>>>(degs_i, bsum);
  scan_sums_k<<<1, 64, 0, stream>>>(bsum, boff);
  scan_final_k<<<49, 256, 0, stream>>>(degs_i, boff, row_start);
  scatter_k<<<3125, 256, 0, stream>>>(src, dst, row_start, fill, csr2);
  cntf_k<<<196, 256, 0, stream>>>(csr2, row_start, efeat, cntf);

  // layer 0 aggregate: atom-encoded h16, no BN
  aggregate_t<0><<<12504, 256, 0, stream>>>(h16, csr2, row_start,
                                            nullptr, nullptr, X16);
  for (int l = 0; l < 5; ++l) {
    gemm_k<<<dim3(MTILES, 2), 256, 0, stream>>>(X16, Wt + l * 65536, cntf,
                                                EWt + l * 8192, b + l * 256,
                                                Y16, Pp);
    stats_finalize_k<<<256, 128, 0, stream>>>(Pp, b + l * 256, gamma + l * 256,
                                              beta + l * 256, scale, shiftv,
                                              sc16, sh16);
    if (l < 4)
      aggregate_t<1><<<12504, 256, 0, stream>>>(Y16, csr2, row_start,
                                                sc16, sh16, X16);
  }

  pool_k<<<128, 512, 0, stream>>>(Y16, gid, scale, shiftv, gpool);
  final_k<<<128, 128, 0, stream>>>(gpool, Wp, bp, out);
}

// Round 17
// 599.507 us; speedup vs baseline: 3.5258x; 1.0215x over previous
//
#include <hip/hip_runtime.h>

#define N_NODESC 50000
#define N_PAD 50176          // 392 * 128
#define N_EDGESC 800000
#define N_GRAPHSC 128
#define EMBEDC 256
#define MTILES 392
#define SLAB ((long)N_PAD * 32)   // halves per 32-col slice slab
#define NRANGE 6272               // N_PAD/8: node range per scatter slice

typedef __attribute__((ext_vector_type(8))) _Float16 hf8;
typedef __attribute__((ext_vector_type(4))) float fx4;

__device__ __forceinline__ float h2f(unsigned short u) {
  _Float16 h = *(_Float16*)&u;
  return (float)h;
}
__device__ __forceinline__ unsigned short f2h(float f) {
  _Float16 h = (_Float16)f;
  return *(unsigned short*)&h;
}
__device__ __forceinline__ unsigned int packh2(float lo, float hi) {
  return (unsigned int)f2h(lo) | ((unsigned int)f2h(hi) << 16);
}

// ------------------------------------------- atom encoder (slice-major h16)
__global__ __launch_bounds__(256) void atom_encode_k(
    const int* __restrict__ nfeat, const float* __restrict__ atom_emb,
    unsigned short* __restrict__ h16)
{
  int w = threadIdx.x >> 6, lane = threadIdx.x & 63;
  int n = blockIdx.x * 4 + w;
  if (n >= N_NODESC) return;
  const int* nf = nfeat + n * 9;
  float ax = 0.f, ay = 0.f, az = 0.f, aw = 0.f;
#pragma unroll
  for (int c = 0; c < 9; ++c) {
    int idx = nf[c];
    const float4* row = (const float4*)(atom_emb + (c * 128 + idx) * EMBEDC);
    float4 v = row[lane];
    ax += v.x; ay += v.y; az += v.z; aw += v.w;
  }
  ushort4 o;
  o.x = f2h(ax); o.y = f2h(ay); o.z = f2h(az); o.w = f2h(aw);
  int col = lane * 4;
  *(ushort4*)(h16 + (long)(col >> 5) * SLAB + (long)n * 32 + (col & 31)) = o;
}

// ---------------------------------------------------------------- degree count
__global__ __launch_bounds__(256) void deg_k(
    const int* __restrict__ dst, int* __restrict__ degs)
{
  int e = blockIdx.x * 256 + threadIdx.x;
  if (e >= N_EDGESC) return;
  atomicAdd(&degs[dst[e]], 1);
}

// ------------------------------------------- parallel 3-phase exclusive scan
__global__ __launch_bounds__(256) void scan_partial_k(
    const int* __restrict__ deg, int* __restrict__ bsum)
{
  __shared__ int buf[256];
  int b = blockIdx.x, t = threadIdx.x;
  int idx0 = b * 1024 + t * 4;
  int s = 0;
#pragma unroll
  for (int i = 0; i < 4; ++i) {
    int idx = idx0 + i;
    if (idx < N_NODESC) s += deg[idx];
  }
  buf[t] = s;
  __syncthreads();
  for (int off = 1; off < 256; off <<= 1) {
    int add = (t >= off) ? buf[t - off] : 0;
    __syncthreads();
    buf[t] += add;
    __syncthreads();
  }
  if (t == 255) bsum[b] = buf[255];
}
__global__ __launch_bounds__(64) void scan_sums_k(
    const int* __restrict__ bsum, int* __restrict__ boff)
{
  __shared__ int buf[64];
  int t = threadIdx.x;
  int v = (t < 49) ? bsum[t] : 0;
  buf[t] = v;
  __syncthreads();
  for (int off = 1; off < 64; off <<= 1) {
    int add = (t >= off) ? buf[t - off] : 0;
    __syncthreads();
    buf[t] += add;
    __syncthreads();
  }
  if (t < 49) boff[t] = buf[t] - v;   // exclusive
  if (t == 48) boff[49] = buf[48];    // total
}
__global__ __launch_bounds__(256) void scan_final_k(
    const int* __restrict__ deg, const int* __restrict__ boff,
    int* __restrict__ row_start)
{
  __shared__ int buf[256];
  int b = blockIdx.x, t = threadIdx.x;
  int idx0 = b * 1024 + t * 4;
  int loc[4];
  int s = 0;
#pragma unroll
  for (int i = 0; i < 4; ++i) {
    int idx = idx0 + i;
    int v = (idx < N_NODESC) ? deg[idx] : 0;
    loc[i] = v; s += v;
  }
  buf[t] = s;
  __syncthreads();
  for (int off = 1; off < 256; off <<= 1) {
    int add = (t >= off) ? buf[t - off] : 0;
    __syncthreads();
    buf[t] += add;
    __syncthreads();
  }
  int run = boff[b] + buf[t] - s;
#pragma unroll
  for (int i = 0; i < 4; ++i) {
    int idx = idx0 + i;
    if (idx < N_NODESC) row_start[idx] = run;
    run += loc[i];
  }
  if (b == 48 && t == 255) row_start[N_NODESC] = boff[49];
}

// ------------------------------------ CSR scatter, range-partitioned by dst
// block b: edge chunk b>>3, node range r = b&7 (bid%8 -> XCD r). All writes
// for range r land in a contiguous ~800KB csr2 slice cached in XCD r's L2 ->
// full-line writebacks instead of 64B/edge random dirtying.
__global__ __launch_bounds__(256) void scatter_k(
    const int* __restrict__ src, const int* __restrict__ dst,
    const int* __restrict__ row_start, int* __restrict__ fill,
    int2* __restrict__ csr2)
{
  int b = blockIdx.x;
  int r = b & 7;
  int e = (b >> 3) * 256 + threadIdx.x;
  if (e >= N_EDGESC) return;
  int d = dst[e];
  int lo = r * NRANGE;
  if (d < lo || d >= lo + NRANGE) return;
  int pos = row_start[d] + atomicAdd(&fill[d], 1);
  csr2[pos] = make_int2(src[e], e);
}

// ------------------- per-node edge-feature histogram -> fp16 cnt/(deg+1)
__global__ __launch_bounds__(256) void cntf_k(
    const int2* __restrict__ csr2, const int* __restrict__ row_start,
    const int* __restrict__ efeat, unsigned short* __restrict__ cntf)
{
  __shared__ int lc[256 * 25];
  int t = threadIdx.x;
  int n = blockIdx.x * 256 + t;          // 196*256 == 50176 == N_PAD
  int base = t * 25;
#pragma unroll
  for (int j = 0; j < 24; ++j) lc[base + j] = 0;
  float inv = 0.f;
  if (n < N_NODESC) {
    int s0 = row_start[n], s1 = row_start[n + 1];
    inv = 1.0f / (float)(s1 - s0 + 1);
    for (int e = s0; e < s1; ++e) {
      int eid = csr2[e].y;
      int v0 = efeat[eid * 3 + 0];
      int v1 = efeat[eid * 3 + 1];
      int v2 = efeat[eid * 3 + 2];
      lc[base + v0]++;
      lc[base + 8 + v1]++;
      lc[base + 16 + v2]++;
    }
  }
  unsigned int* o = (unsigned int*)(cntf + (long)n * 32);
#pragma unroll
  for (int j = 0; j < 12; ++j)
    o[j] = packh2((float)lc[base + 2 * j] * inv, (float)lc[base + 2 * j + 1] * inv);
#pragma unroll
  for (int j = 12; j < 16; ++j) o[j] = 0u;
}

// ------------------------------------------------ W transpose + fp16 convert
__global__ __launch_bounds__(256) void wprep_k(
    const float* __restrict__ W, unsigned short* __restrict__ Wt)
{
  int tid = blockIdx.x * 256 + threadIdx.x;     // 5*65536
  int l = tid >> 16, r = tid & 65535;
  int n = r >> 8, k = r & 255;
  float w = W[(long)l * 65536 + k * 256 + n];
  Wt[tid] = f2h(w);                             // tid == l*65536 + n*256 + k
}

// ------------------------------ EW[l] = E[l] @ W[l], stored transposed [c'][32]
__global__ __launch_bounds__(256) void ew_k(
    const float* __restrict__ edge_emb, const float* __restrict__ W,
    unsigned short* __restrict__ EWt)
{
  __shared__ float e[256];
  int l = blockIdx.x / 24, j = blockIdx.x % 24;
  int c = threadIdx.x;
  e[c] = edge_emb[(long)l * 6144 + j * 256 + c];
  __syncthreads();
  const float* Wl = W + (long)l * 65536;
  float acc = 0.f;
#pragma unroll 8
  for (int k = 0; k < 256; ++k) acc += e[k] * Wl[k * 256 + c];
  EWt[((long)l * 256 + c) * 32 + j] = f2h(acc);
}

// ---------------------------------------------------------------- aggregation
// XCD-sliced (slice = blockIdx%8 -> slab L2-resident per XCD). Wave = 8 nodes
// x 8 lanes (2 edge-groups x 4 chunks of 16B). Pure gather+add: histogram term
// folded into GEMM (K=288). Packed fp16 accumulate, single fp32 flush.
template<int FUSE_BN>
__device__ __forceinline__ hf8 bnval(const uint4 u, const hf8 scv, const hf8 shv)
{
  union { uint4 u4; hf8 h8; } cv;
  cv.u4 = u;
  hf8 y = cv.h8;
  if (FUSE_BN) {
    y = y * scv + shv;                        // v_pk_fma_f16 x4
    y = __builtin_elementwise_max(y, (hf8)0); // v_pk_max_f16 x4
  }
  return y;
}

template<int FUSE_BN>
__global__ __launch_bounds__(256) void aggregate_t(
    const unsigned short* __restrict__ tab_base,
    const int2* __restrict__ csr2, const int* __restrict__ row_start,
    const unsigned short* __restrict__ sc16,
    const unsigned short* __restrict__ sh16,
    unsigned short* __restrict__ X16)
{
  int bid = blockIdx.x;
  int s = bid & 7;                               // slice == XCD (heuristic)
  int grp = bid >> 3;
  int lane = threadIdx.x & 63;
  int w = threadIdx.x >> 6;
  int nd = lane >> 3;            // node within wave (8)
  int g = (lane >> 2) & 1;       // edge group (2)
  int q = lane & 3;              // 16B chunk (4)
  int n = grp * 32 + w * 8 + nd; // 1563 grps * 32 = 50016 >= 50000
  if (n >= N_NODESC) return;
  const unsigned short* tab = tab_base + (long)s * SLAB;
  hf8 scv = (hf8)0, shv = (hf8)0;
  if (FUSE_BN) {
    scv = *(const hf8*)(sc16 + s * 32 + q * 8);
    shv = *(const hf8*)(sh16 + s * 32 + q * 8);
  }
  int s0 = row_start[n], s1 = row_start[n + 1];
  hf8 hacc = (hf8)0;                             // packed fp16 accumulator
  if (g == 0) {                                  // self row (once, pre-reduce)
    uint4 u = *(const uint4*)(tab + (long)n * 32 + q * 8);
    hacc = hacc + bnval<FUSE_BN>(u, scv, shv);
  }
  int e = s0 + g;
  for (; e + 2 < s1; e += 4) {                   // 2 edges in flight per lane
    int i0 = csr2[e].x;
    int i1 = csr2[e + 2].x;
    uint4 u0 = *(const uint4*)(tab + (long)i0 * 32 + q * 8);
    uint4 u1 = *(const uint4*)(tab + (long)i1 * 32 + q * 8);
    hacc = hacc + bnval<FUSE_BN>(u0, scv, shv);
    hacc = hacc + bnval<FUSE_BN>(u1, scv, shv);
  }
  if (e < s1) {
    int i0 = csr2[e].x;
    uint4 u = *(const uint4*)(tab + (long)i0 * 32 + q * 8);
    hacc = hacc + bnval<FUSE_BN>(u, scv, shv);
  }
  // fp32 flush, then reduce over the 2 edge-groups (lane bit 2)
  float a[8];
#pragma unroll
  for (int k = 0; k < 8; ++k) a[k] = (float)hacc[k];
#pragma unroll
  for (int k = 0; k < 8; ++k) a[k] += __shfl_xor(a[k], 4);
  if (g == 0) {                                  // 4 lanes/node write 64B
    float inv = 1.0f / (float)(s1 - s0 + 1);
    uint4 o;
    o.x = packh2(a[0] * inv, a[1] * inv);
    o.y = packh2(a[2] * inv, a[3] * inv);
    o.z = packh2(a[4] * inv, a[5] * inv);
    o.w = packh2(a[6] * inv, a[7] * inv);
    *(uint4*)(X16 + (long)s * SLAB + (long)n * 32 + q * 8) = o;
  }
}

// ---------------------------------------------------------------- MFMA GEMM fp16
// Y16 = fp16([X | cntf] @ [W ; EW] + b), K = 256 + 32(24 used).
__global__ __launch_bounds__(256) void gemm_k(
    const unsigned short* __restrict__ X16, const unsigned short* __restrict__ Bt,
    const unsigned short* __restrict__ cntf, const unsigned short* __restrict__ EWt,
    const float* __restrict__ bl, unsigned short* __restrict__ Y16,
    float* __restrict__ Pp)
{
  __shared__ unsigned short As[128 * 72];
  __shared__ unsigned short Bs[128 * 72];
  __shared__ float red_s[256];
  __shared__ float red_q[256];

  int t = threadIdx.x;
  int bm = blockIdx.x, bn = blockIdx.y;
  int row0 = bm * 128, nc0 = bn * 128;
  int w = t >> 6, l = t & 63;
  int wr = w >> 1, wc = w & 1;
  int lr = l & 15, lk = l >> 4;

  fx4 acc[4][4];
#pragma unroll
  for (int i = 0; i < 4; ++i)
#pragma unroll
    for (int j = 0; j < 4; ++j) acc[i][j] = (fx4){0.f, 0.f, 0.f, 0.f};

  for (int kb = 0; kb < 5; ++kb) {
    __syncthreads();
    if (kb < 4) {
      int kc = kb * 64;
#pragma unroll
      for (int q = 0; q < 2; ++q) {
        int id = q * 256 + t;
        int r = id >> 2, c16 = (id & 3) << 4;
        int ktot = kc + c16;
        long gA = (long)(ktot >> 5) * SLAB + (long)(row0 + r) * 32 + (ktot & 31);
        long gB = (long)(nc0 + r) * 256 + ktot;
        *(uint4*)&As[r * 72 + c16] = *(const uint4*)(X16 + gA);
        *(uint4*)&As[r * 72 + c16 + 8] = *(const uint4*)(X16 + gA + 8);
        *(uint4*)&Bs[r * 72 + c16] = *(const uint4*)(Bt + gB);
        *(uint4*)&Bs[r * 72 + c16 + 8] = *(const uint4*)(Bt + gB + 8);
      }
    } else {
#pragma unroll
      for (int q = 0; q < 2; ++q) {
        int id = q * 256 + t;
        int r = id >> 2, c8 = (id & 3) << 3;
        *(uint4*)&As[r * 72 + c8] = *(const uint4*)(cntf + (long)(row0 + r) * 32 + c8);
        *(uint4*)&Bs[r * 72 + c8] = *(const uint4*)(EWt + (long)(nc0 + r) * 32 + c8);
      }
    }
    __syncthreads();
    int nks = (kb < 4) ? 2 : 1;
    for (int ks = 0; ks < nks; ++ks) {
      int ko = ks * 32 + lk * 8;
      hf8 af[4], bf[4];
#pragma unroll
      for (int f = 0; f < 4; ++f) {
        af[f] = *(const hf8*)&As[(wr * 64 + f * 16 + lr) * 72 + ko];
        bf[f] = *(const hf8*)&Bs[(wc * 64 + f * 16 + lr) * 72 + ko];
      }
#pragma unroll
      for (int fm = 0; fm < 4; ++fm)
#pragma unroll
        for (int fn = 0; fn < 4; ++fn)
          acc[fm][fn] = __builtin_amdgcn_mfma_f32_16x16x32_f16(
              af[fm], bf[fn], acc[fm][fn], 0, 0, 0);
    }
  }

  float bcol[4];
#pragma unroll
  for (int fn = 0; fn < 4; ++fn) bcol[fn] = bl[nc0 + wc * 64 + fn * 16 + lr];
  float sp[4] = {0.f, 0.f, 0.f, 0.f}, qp[4] = {0.f, 0.f, 0.f, 0.f};
#pragma unroll
  for (int fm = 0; fm < 4; ++fm)
#pragma unroll
    for (int fn = 0; fn < 4; ++fn) {
      int cl = wc * 64 + fn * 16 + lr;
      int col = nc0 + cl;
      long ybase = (long)(col >> 5) * SLAB + (col & 31);
#pragma unroll
      for (int j = 0; j < 4; ++j) {
        int rl = wr * 64 + fm * 16 + lk * 4 + j;
        float v = acc[fm][fn][j] + bcol[fn];
        Y16[ybase + (long)(row0 + rl) * 32] = f2h(v);
        sp[fn] += v; qp[fn] += v * v;
      }
    }
#pragma unroll
  for (int fn = 0; fn < 4; ++fn) {
    sp[fn] += __shfl_xor(sp[fn], 16);
    sp[fn] += __shfl_xor(sp[fn], 32);
    qp[fn] += __shfl_xor(qp[fn], 16);
    qp[fn] += __shfl_xor(qp[fn], 32);
  }
  if (lk == 0) {
#pragma unroll
    for (int fn = 0; fn < 4; ++fn) {
      red_s[w * 64 + fn * 16 + lr] = sp[fn];
      red_q[w * 64 + fn * 16 + lr] = qp[fn];
    }
  }
  __syncthreads();
  if (t < 128) {
    float s = red_s[t] + red_s[128 + t];
    float q = red_q[t] + red_q[128 + t];
    float* p = Pp + (bm * 2 + bn) * 256;
    p[t] = s;
    p[128 + t] = q;
  }
}

// --------------------------- BN stats reduce + finalize (256 blocks, parallel)
__global__ __launch_bounds__(128) void stats_finalize_k(
    const float* __restrict__ Pp, const float* __restrict__ bl,
    const float* __restrict__ gamma, const float* __restrict__ beta,
    float* __restrict__ scale, float* __restrict__ shiftv,
    unsigned short* __restrict__ sc16, unsigned short* __restrict__ sh16)
{
  __shared__ float red_s[128];
  __shared__ float red_q[128];
  int c = blockIdx.x;                 // one column per block
  int half = c >> 7, cl = c & 127;
  int t = threadIdx.x;
  float s = 0.f, q = 0.f;
  for (int bm = t; bm < MTILES; bm += 128) {
    const float* p = Pp + (bm * 2 + half) * 256;
    s += p[cl];
    q += p[128 + cl];
  }
  red_s[t] = s; red_q[t] = q;
  __syncthreads();
#pragma unroll
  for (int off = 64; off > 0; off >>= 1) {
    if (t < off) {
      red_s[t] += red_s[t + off];
      red_q[t] += red_q[t + off];
    }
    __syncthreads();
  }
  if (t == 0) {
    s = red_s[0]; q = red_q[0];
    float bc = bl[c];
    s -= (float)(N_PAD - N_NODESC) * bc;
    q -= (float)(N_PAD - N_NODESC) * bc * bc;
    const float invN = 1.0f / (float)N_NODESC;
    float mu = s * invN;
    float var = q * invN - mu * mu;
    float rsq = rsqrtf(var + 1e-5f);
    float sc = gamma[c] * rsq;
    float sh = beta[c] - mu * sc;
    scale[c] = sc;
    shiftv[c] = sh;
    sc16[c] = f2h(sc);
    sh16[c] = f2h(sh);
  }
}

// ---------------------------------------------------------------- mean pooling
__device__ __forceinline__ int lower_bound_g(const int* gid, int n, int g)
{
  int lo = 0, hi = n;
  while (lo < hi) {
    int mid = (lo + hi) >> 1;
    if (gid[mid] < g) lo = mid + 1; else hi = mid;
  }
  return lo;
}

__global__ __launch_bounds__(512) void pool_k(
    const unsigned short* __restrict__ Y16, const int* __restrict__ gid,
    const float* __restrict__ scale, const float* __restrict__ shiftv,
    float* __restrict__ gpool)
{
  __shared__ float red[8 * 256];
  int g = blockIdx.x;
  int lo = lower_bound_g(gid, N_NODESC, g);
  int hi = lower_bound_g(gid, N_NODESC, g + 1);
  int t = threadIdx.x;
  int w = t >> 6, lane = t & 63;
  int col = lane * 4;
  long ybase = (long)(col >> 5) * SLAB + (col & 31);
  float4 sc = *(const float4*)(scale + col);
  float4 sh = *(const float4*)(shiftv + col);
  float a0 = 0.f, a1 = 0.f, a2 = 0.f, a3 = 0.f;
  for (int r = lo + w; r < hi; r += 8) {
    ushort4 u = *(const ushort4*)(Y16 + ybase + (long)r * 32);
    a0 += fmaxf(0.f, h2f(u.x) * sc.x + sh.x);
    a1 += fmaxf(0.f, h2f(u.y) * sc.y + sh.y);
    a2 += fmaxf(0.f, h2f(u.z) * sc.z + sh.z);
    a3 += fmaxf(0.f, h2f(u.w) * sc.w + sh.w);
  }
  *(float4*)&red[w * 256 + col] = make_float4(a0, a1, a2, a3);
  __syncthreads();
  if (t < 256) {
    float s = 0.f;
#pragma unroll
    for (int j = 0; j < 8; ++j) s += red[j * 256 + t];
    int c = hi - lo;
    gpool[g * 256 + t] = s / (float)(c > 0 ? c : 1);
  }
}

// ---------------------------------------------------------------- final proj
__global__ __launch_bounds__(128) void final_k(
    const float* __restrict__ gpool, const float* __restrict__ Wp,
    const float* __restrict__ bp, float* __restrict__ out)
{
  __shared__ float gr[256];
  int g = blockIdx.x, t = threadIdx.x;
  gr[t] = gpool[g * 256 + t];
  gr[t + 128] = gpool[g * 256 + t + 128];
  __syncthreads();
  float acc = bp[t];
#pragma unroll 8
  for (int k = 0; k < 256; ++k) acc += gr[k] * Wp[k * 128 + t];
  out[g * 128 + t] = acc;
}

// ---------------------------------------------------------------- launcher
extern "C" void kernel_launch(void* const* d_in, const int* in_sizes, int n_in,
                              void* d_out, int out_size, void* d_ws, size_t ws_size,
                              hipStream_t stream)
{
  (void)in_sizes; (void)n_in; (void)out_size; (void)ws_size;
  const int* nfeat = (const int*)d_in[0];
  const int* efeat = (const int*)d_in[1];
  const int* src = (const int*)d_in[2];
  const int* dst = (const int*)d_in[3];
  const int* gid = (const int*)d_in[4];
  const float* atom_emb = (const float*)d_in[5];
  const float* edge_emb = (const float*)d_in[6];
  const float* W = (const float*)d_in[7];
  const float* b = (const float*)d_in[8];
  const float* gamma = (const float*)d_in[9];
  const float* beta = (const float*)d_in[10];
  const float* Wp = (const float*)d_in[11];
  const float* bp = (const float*)d_in[12];
  float* out = (float*)d_out;

  char* ws = (char*)d_ws;
  unsigned short* h16 = (unsigned short*)ws; ws += (size_t)N_PAD * 512;
  unsigned short* Y16 = (unsigned short*)ws; ws += (size_t)N_PAD * 512;
  unsigned short* X16 = (unsigned short*)ws; ws += (size_t)N_PAD * 512;
  unsigned short* Wt = (unsigned short*)ws; ws += 5 * 65536 * 2;
  unsigned short* EWt = (unsigned short*)ws; ws += 5 * 256 * 32 * 2;
  unsigned short* cntf = (unsigned short*)ws; ws += (size_t)N_PAD * 32 * 2;
  int2* csr2 = (int2*)ws; ws += 6400000;
  int* row_start = (int*)ws; ws += 200064;
  int* degs_i = (int*)ws; ws += 200064;
  int* fill = (int*)ws; ws += 200064;
  int* bsum = (int*)ws; ws += 256;
  int* boff = (int*)ws; ws += 256;
  float* Pp = (float*)ws; ws += MTILES * 2 * 256 * 4;
  float* scale = (float*)ws; ws += 1024;
  float* shiftv = (float*)ws; ws += 1024;
  unsigned short* sc16 = (unsigned short*)ws; ws += 512;
  unsigned short* sh16 = (unsigned short*)ws; ws += 512;
  float* gpool = (float*)ws; ws += 131072;

  hipMemsetAsync(degs_i, 0, 200000, stream);
  hipMemsetAsync(fill, 0, 200000, stream);
  // zero X16 pad rows in each slice slab so GEMM pad output is exactly b[c]
  for (int s = 0; s < 8; ++s)
    hipMemsetAsync(X16 + (size_t)s * SLAB + (size_t)N_NODESC * 32, 0,
                   (size_t)(N_PAD - N_NODESC) * 64, stream);

  wprep_k<<<1280, 256, 0, stream>>>(W, Wt);
  ew_k<<<120, 256, 0, stream>>>(edge_emb, W, EWt);
  atom_encode_k<<<12500, 256, 0, stream>>>(nfeat, atom_emb, h16);
  deg_k<<<3125, 256, 0, stream>>>(dst, degs_i);
  scan_partial_k<<<49, 256, 0, stream>>>(degs_i, bsum);
  scan_sums_k<<<1, 64, 0, stream>>>(bsum, boff);
  scan_final_k<<<49, 256, 0, stream>>>(degs_i, boff, row_start);
  scatter_k<<<25000, 256, 0, stream>>>(src, dst, row_start, fill, csr2);
  cntf_k<<<196, 256, 0, stream>>>(csr2, row_start, efeat, cntf);

  // layer 0 aggregate: atom-encoded h16, no BN
  aggregate_t<0><<<12504, 256, 0, stream>>>(h16, csr2, row_start,
                                            nullptr, nullptr, X16);
  for (int l = 0; l < 5; ++l) {
    gemm_k<<<dim3(MTILES, 2), 256, 0, stream>>>(X16, Wt + l * 65536, cntf,
                                                EWt + l * 8192, b + l * 256,
                                                Y16, Pp);
    stats_finalize_k<<<256, 128, 0, stream>>>(Pp, b + l * 256, gamma + l * 256,
                                              beta + l * 256, scale, shiftv,
                                              sc16, sh16);
    if (l < 4)
      aggregate_t<1><<<12504, 256, 0, stream>>>(Y16, csr2, row_start,
                                                sc16, sh16, X16);
  }

  pool_k<<<128, 512, 0, stream>>>(Y16, gid, scale, shiftv, gpool);
  final_k<<<128, 128, 0, stream>>>(gpool, Wp, bp, out);
}

// Round 18
// 568.983 us; speedup vs baseline: 3.7149x; 1.0536x over previous
//
#include <hip/hip_runtime.h>

#define N_NODESC 50000
#define N_PAD 50176          // 392 * 128
#define N_EDGESC 800000
#define N_GRAPHSC 128
#define EMBEDC 256
#define MTILES 392
#define SLAB ((long)N_PAD * 32)   // halves per 32-col slice slab
#define NRANGE 6272               // N_PAD/8: node range per scatter slice

typedef __attribute__((ext_vector_type(8))) _Float16 hf8;
typedef __attribute__((ext_vector_type(4))) float fx4;

__device__ __forceinline__ float h2f(unsigned short u) {
  _Float16 h = *(_Float16*)&u;
  return (float)h;
}
__device__ __forceinline__ unsigned short f2h(float f) {
  _Float16 h = (_Float16)f;
  return *(unsigned short*)&h;
}
__device__ __forceinline__ unsigned int packh2(float lo, float hi) {
  return (unsigned int)f2h(lo) | ((unsigned int)f2h(hi) << 16);
}

// ------------------------------------------- atom encoder (slice-major h16)
__global__ __launch_bounds__(256) void atom_encode_k(
    const int* __restrict__ nfeat, const float* __restrict__ atom_emb,
    unsigned short* __restrict__ h16)
{
  int w = threadIdx.x >> 6, lane = threadIdx.x & 63;
  int n = blockIdx.x * 4 + w;
  if (n >= N_NODESC) return;
  const int* nf = nfeat + n * 9;
  float ax = 0.f, ay = 0.f, az = 0.f, aw = 0.f;
#pragma unroll
  for (int c = 0; c < 9; ++c) {
    int idx = nf[c];
    const float4* row = (const float4*)(atom_emb + (c * 128 + idx) * EMBEDC);
    float4 v = row[lane];
    ax += v.x; ay += v.y; az += v.z; aw += v.w;
  }
  ushort4 o;
  o.x = f2h(ax); o.y = f2h(ay); o.z = f2h(az); o.w = f2h(aw);
  int col = lane * 4;
  *(ushort4*)(h16 + (long)(col >> 5) * SLAB + (long)n * 32 + (col & 31)) = o;
}

// ---------------------------------------------------------------- degree count
__global__ __launch_bounds__(256) void deg_k(
    const int* __restrict__ dst, int* __restrict__ degs)
{
  int e = blockIdx.x * 256 + threadIdx.x;
  if (e >= N_EDGESC) return;
  atomicAdd(&degs[dst[e]], 1);
}

// ------------------------------------------- parallel 3-phase exclusive scan
__global__ __launch_bounds__(256) void scan_partial_k(
    const int* __restrict__ deg, int* __restrict__ bsum)
{
  __shared__ int buf[256];
  int b = blockIdx.x, t = threadIdx.x;
  int idx0 = b * 1024 + t * 4;
  int s = 0;
#pragma unroll
  for (int i = 0; i < 4; ++i) {
    int idx = idx0 + i;
    if (idx < N_NODESC) s += deg[idx];
  }
  buf[t] = s;
  __syncthreads();
  for (int off = 1; off < 256; off <<= 1) {
    int add = (t >= off) ? buf[t - off] : 0;
    __syncthreads();
    buf[t] += add;
    __syncthreads();
  }
  if (t == 255) bsum[b] = buf[255];
}
__global__ __launch_bounds__(64) void scan_sums_k(
    const int* __restrict__ bsum, int* __restrict__ boff)
{
  __shared__ int buf[64];
  int t = threadIdx.x;
  int v = (t < 49) ? bsum[t] : 0;
  buf[t] = v;
  __syncthreads();
  for (int off = 1; off < 64; off <<= 1) {
    int add = (t >= off) ? buf[t - off] : 0;
    __syncthreads();
    buf[t] += add;
    __syncthreads();
  }
  if (t < 49) boff[t] = buf[t] - v;   // exclusive
  if (t == 48) boff[49] = buf[48];    // total
}
__global__ __launch_bounds__(256) void scan_final_k(
    const int* __restrict__ deg, const int* __restrict__ boff,
    int* __restrict__ row_start)
{
  __shared__ int buf[256];
  int b = blockIdx.x, t = threadIdx.x;
  int idx0 = b * 1024 + t * 4;
  int loc[4];
  int s = 0;
#pragma unroll
  for (int i = 0; i < 4; ++i) {
    int idx = idx0 + i;
    int v = (idx < N_NODESC) ? deg[idx] : 0;
    loc[i] = v; s += v;
  }
  buf[t] = s;
  __syncthreads();
  for (int off = 1; off < 256; off <<= 1) {
    int add = (t >= off) ? buf[t - off] : 0;
    __syncthreads();
    buf[t] += add;
    __syncthreads();
  }
  int run = boff[b] + buf[t] - s;
#pragma unroll
  for (int i = 0; i < 4; ++i) {
    int idx = idx0 + i;
    if (idx < N_NODESC) row_start[idx] = run;
    run += loc[i];
  }
  if (b == 48 && t == 255) row_start[N_NODESC] = boff[49];
}

// ------------------------------------ CSR scatter, range-partitioned by dst
// block b: edge chunk b>>3, node range r = b&7 (bid%8 -> XCD r). All writes
// for range r land in contiguous csr slices cached in XCD r's L2. Separate
// csrc/ceid arrays so aggregate fetches only 4B/edge of index traffic.
__global__ __launch_bounds__(256) void scatter_k(
    const int* __restrict__ src, const int* __restrict__ dst,
    const int* __restrict__ row_start, int* __restrict__ fill,
    int* __restrict__ csrc, int* __restrict__ ceid)
{
  int b = blockIdx.x;
  int r = b & 7;
  int e = (b >> 3) * 256 + threadIdx.x;
  if (e >= N_EDGESC) return;
  int d = dst[e];
  int lo = r * NRANGE;
  if (d < lo || d >= lo + NRANGE) return;
  int pos = row_start[d] + atomicAdd(&fill[d], 1);
  csrc[pos] = src[e];
  ceid[pos] = e;
}

// ------------------- per-node edge-feature histogram -> fp16 cnt/(deg+1)
__global__ __launch_bounds__(256) void cntf_k(
    const int* __restrict__ ceid, const int* __restrict__ row_start,
    const int* __restrict__ efeat, unsigned short* __restrict__ cntf)
{
  __shared__ int lc[256 * 25];
  int t = threadIdx.x;
  int n = blockIdx.x * 256 + t;          // 196*256 == 50176 == N_PAD
  int base = t * 25;
#pragma unroll
  for (int j = 0; j < 24; ++j) lc[base + j] = 0;
  float inv = 0.f;
  if (n < N_NODESC) {
    int s0 = row_start[n], s1 = row_start[n + 1];
    inv = 1.0f / (float)(s1 - s0 + 1);
    for (int e = s0; e < s1; ++e) {
      int eid = ceid[e];
      int v0 = efeat[eid * 3 + 0];
      int v1 = efeat[eid * 3 + 1];
      int v2 = efeat[eid * 3 + 2];
      lc[base + v0]++;
      lc[base + 8 + v1]++;
      lc[base + 16 + v2]++;
    }
  }
  unsigned int* o = (unsigned int*)(cntf + (long)n * 32);
#pragma unroll
  for (int j = 0; j < 12; ++j)
    o[j] = packh2((float)lc[base + 2 * j] * inv, (float)lc[base + 2 * j + 1] * inv);
#pragma unroll
  for (int j = 12; j < 16; ++j) o[j] = 0u;
}

// ------------------------------------------------ W transpose + fp16 convert
__global__ __launch_bounds__(256) void wprep_k(
    const float* __restrict__ W, unsigned short* __restrict__ Wt)
{
  int tid = blockIdx.x * 256 + threadIdx.x;     // 5*65536
  int l = tid >> 16, r = tid & 65535;
  int n = r >> 8, k = r & 255;
  float w = W[(long)l * 65536 + k * 256 + n];
  Wt[tid] = f2h(w);                             // tid == l*65536 + n*256 + k
}

// ------------------------------ EW[l] = E[l] @ W[l], stored transposed [c'][32]
__global__ __launch_bounds__(256) void ew_k(
    const float* __restrict__ edge_emb, const float* __restrict__ W,
    unsigned short* __restrict__ EWt)
{
  __shared__ float e[256];
  int l = blockIdx.x / 24, j = blockIdx.x % 24;
  int c = threadIdx.x;
  e[c] = edge_emb[(long)l * 6144 + j * 256 + c];
  __syncthreads();
  const float* Wl = W + (long)l * 65536;
  float acc = 0.f;
#pragma unroll 8
  for (int k = 0; k < 256; ++k) acc += e[k] * Wl[k * 256 + c];
  EWt[((long)l * 256 + c) * 32 + j] = f2h(acc);
}

// ---------------------------------------------------------------- aggregation
// XCD-sliced (slice = blockIdx%8 -> slab L2-resident per XCD). Wave = 8 nodes
// x 8 lanes (2 edge-groups x 4 chunks of 16B). Pure gather+add: histogram term
// folded into GEMM (K=288). Packed fp16 accumulate, single fp32 flush.
template<int FUSE_BN>
__device__ __forceinline__ hf8 bnval(const uint4 u, const hf8 scv, const hf8 shv)
{
  union { uint4 u4; hf8 h8; } cv;
  cv.u4 = u;
  hf8 y = cv.h8;
  if (FUSE_BN) {
    y = y * scv + shv;                        // v_pk_fma_f16 x4
    y = __builtin_elementwise_max(y, (hf8)0); // v_pk_max_f16 x4
  }
  return y;
}

template<int FUSE_BN>
__global__ __launch_bounds__(256) void aggregate_t(
    const unsigned short* __restrict__ tab_base,
    const int* __restrict__ csrc, const int* __restrict__ row_start,
    const unsigned short* __restrict__ sc16,
    const unsigned short* __restrict__ sh16,
    unsigned short* __restrict__ X16)
{
  int bid = blockIdx.x;
  int s = bid & 7;                               // slice == XCD (heuristic)
  int grp = bid >> 3;
  int lane = threadIdx.x & 63;
  int w = threadIdx.x >> 6;
  int nd = lane >> 3;            // node within wave (8)
  int g = (lane >> 2) & 1;       // edge group (2)
  int q = lane & 3;              // 16B chunk (4)
  int n = grp * 32 + w * 8 + nd; // 1563 grps * 32 = 50016 >= 50000
  if (n >= N_NODESC) return;
  const unsigned short* tab = tab_base + (long)s * SLAB;
  hf8 scv = (hf8)0, shv = (hf8)0;
  if (FUSE_BN) {
    scv = *(const hf8*)(sc16 + s * 32 + q * 8);
    shv = *(const hf8*)(sh16 + s * 32 + q * 8);
  }
  int s0 = row_start[n], s1 = row_start[n + 1];
  hf8 hacc = (hf8)0;                             // packed fp16 accumulator
  if (g == 0) {                                  // self row (once, pre-reduce)
    uint4 u = *(const uint4*)(tab + (long)n * 32 + q * 8);
    hacc = hacc + bnval<FUSE_BN>(u, scv, shv);
  }
  int e = s0 + g;
  for (; e + 2 < s1; e += 4) {                   // 2 edges in flight per lane
    int i0 = csrc[e];
    int i1 = csrc[e + 2];
    uint4 u0 = *(const uint4*)(tab + (long)i0 * 32 + q * 8);
    uint4 u1 = *(const uint4*)(tab + (long)i1 * 32 + q * 8);
    hacc = hacc + bnval<FUSE_BN>(u0, scv, shv);
    hacc = hacc + bnval<FUSE_BN>(u1, scv, shv);
  }
  if (e < s1) {
    int i0 = csrc[e];
    uint4 u = *(const uint4*)(tab + (long)i0 * 32 + q * 8);
    hacc = hacc + bnval<FUSE_BN>(u, scv, shv);
  }
  // fp32 flush, then reduce over the 2 edge-groups (lane bit 2)
  float a[8];
#pragma unroll
  for (int k = 0; k < 8; ++k) a[k] = (float)hacc[k];
#pragma unroll
  for (int k = 0; k < 8; ++k) a[k] += __shfl_xor(a[k], 4);
  if (g == 0) {                                  // 4 lanes/node write 64B
    float inv = 1.0f / (float)(s1 - s0 + 1);
    uint4 o;
    o.x = packh2(a[0] * inv, a[1] * inv);
    o.y = packh2(a[2] * inv, a[3] * inv);
    o.z = packh2(a[4] * inv, a[5] * inv);
    o.w = packh2(a[6] * inv, a[7] * inv);
    *(uint4*)(X16 + (long)s * SLAB + (long)n * 32 + q * 8) = o;
  }
}

// ---------------------------------------------------------------- MFMA GEMM fp16
// Y16 = fp16([X | cntf] @ [W ; EW] + b), K = 256 + 32(24 used).
__global__ __launch_bounds__(256) void gemm_k(
    const unsigned short* __restrict__ X16, const unsigned short* __restrict__ Bt,
    const unsigned short* __restrict__ cntf, const unsigned short* __restrict__ EWt,
    const float* __restrict__ bl, unsigned short* __restrict__ Y16,
    float* __restrict__ Pp)
{
  __shared__ unsigned short As[128 * 72];
  __shared__ unsigned short Bs[128 * 72];
  __shared__ float red_s[256];
  __shared__ float red_q[256];

  int t = threadIdx.x;
  int bm = blockIdx.x, bn = blockIdx.y;
  int row0 = bm * 128, nc0 = bn * 128;
  int w = t >> 6, l = t & 63;
  int wr = w >> 1, wc = w & 1;
  int lr = l & 15, lk = l >> 4;

  fx4 acc[4][4];
#pragma unroll
  for (int i = 0; i < 4; ++i)
#pragma unroll
    for (int j = 0; j < 4; ++j) acc[i][j] = (fx4){0.f, 0.f, 0.f, 0.f};

  for (int kb = 0; kb < 5; ++kb) {
    __syncthreads();
    if (kb < 4) {
      int kc = kb * 64;
#pragma unroll
      for (int q = 0; q < 2; ++q) {
        int id = q * 256 + t;
        int r = id >> 2, c16 = (id & 3) << 4;
        int ktot = kc + c16;
        long gA = (long)(ktot >> 5) * SLAB + (long)(row0 + r) * 32 + (ktot & 31);
        long gB = (long)(nc0 + r) * 256 + ktot;
        *(uint4*)&As[r * 72 + c16] = *(const uint4*)(X16 + gA);
        *(uint4*)&As[r * 72 + c16 + 8] = *(const uint4*)(X16 + gA + 8);
        *(uint4*)&Bs[r * 72 + c16] = *(const uint4*)(Bt + gB);
        *(uint4*)&Bs[r * 72 + c16 + 8] = *(const uint4*)(Bt + gB + 8);
      }
    } else {
#pragma unroll
      for (int q = 0; q < 2; ++q) {
        int id = q * 256 + t;
        int r = id >> 2, c8 = (id & 3) << 3;
        *(uint4*)&As[r * 72 + c8] = *(const uint4*)(cntf + (long)(row0 + r) * 32 + c8);
        *(uint4*)&Bs[r * 72 + c8] = *(const uint4*)(EWt + (long)(nc0 + r) * 32 + c8);
      }
    }
    __syncthreads();
    int nks = (kb < 4) ? 2 : 1;
    for (int ks = 0; ks < nks; ++ks) {
      int ko = ks * 32 + lk * 8;
      hf8 af[4], bf[4];
#pragma unroll
      for (int f = 0; f < 4; ++f) {
        af[f] = *(const hf8*)&As[(wr * 64 + f * 16 + lr) * 72 + ko];
        bf[f] = *(const hf8*)&Bs[(wc * 64 + f * 16 + lr) * 72 + ko];
      }
#pragma unroll
      for (int fm = 0; fm < 4; ++fm)
#pragma unroll
        for (int fn = 0; fn < 4; ++fn)
          acc[fm][fn] = __builtin_amdgcn_mfma_f32_16x16x32_f16(
              af[fm], bf[fn], acc[fm][fn], 0, 0, 0);
    }
  }

  float bcol[4];
#pragma unroll
  for (int fn = 0; fn < 4; ++fn) bcol[fn] = bl[nc0 + wc * 64 + fn * 16 + lr];
  float sp[4] = {0.f, 0.f, 0.f, 0.f}, qp[4] = {0.f, 0.f, 0.f, 0.f};
#pragma unroll
  for (int fm = 0; fm < 4; ++fm)
#pragma unroll
    for (int fn = 0; fn < 4; ++fn) {
      int cl = wc * 64 + fn * 16 + lr;
      int col = nc0 + cl;
      long ybase = (long)(col >> 5) * SLAB + (col & 31);
#pragma unroll
      for (int j = 0; j < 4; ++j) {
        int rl = wr * 64 + fm * 16 + lk * 4 + j;
        float v = acc[fm][fn][j] + bcol[fn];
        Y16[ybase + (long)(row0 + rl) * 32] = f2h(v);
        sp[fn] += v; qp[fn] += v * v;
      }
    }
#pragma unroll
  for (int fn = 0; fn < 4; ++fn) {
    sp[fn] += __shfl_xor(sp[fn], 16);
    sp[fn] += __shfl_xor(sp[fn], 32);
    qp[fn] += __shfl_xor(qp[fn], 16);
    qp[fn] += __shfl_xor(qp[fn], 32);
  }
  if (lk == 0) {
#pragma unroll
    for (int fn = 0; fn < 4; ++fn) {
      red_s[w * 64 + fn * 16 + lr] = sp[fn];
      red_q[w * 64 + fn * 16 + lr] = qp[fn];
    }
  }
  __syncthreads();
  if (t < 128) {
    float s = red_s[t] + red_s[128 + t];
    float q = red_q[t] + red_q[128 + t];
    float* p = Pp + (bm * 2 + bn) * 256;
    p[t] = s;
    p[128 + t] = q;
  }
}

// --------------------------- BN stats reduce + finalize (256 blocks, parallel)
__global__ __launch_bounds__(128) void stats_finalize_k(
    const float* __restrict__ Pp, const float* __restrict__ bl,
    const float* __restrict__ gamma, const float* __restrict__ beta,
    float* __restrict__ scale, float* __restrict__ shiftv,
    unsigned short* __restrict__ sc16, unsigned short* __restrict__ sh16)
{
  __shared__ float red_s[128];
  __shared__ float red_q[128];
  int c = blockIdx.x;                 // one column per block
  int half = c >> 7, cl = c & 127;
  int t = threadIdx.x;
  float s = 0.f, q = 0.f;
  for (int bm = t; bm < MTILES; bm += 128) {
    const float* p = Pp + (bm * 2 + half) * 256;
    s += p[cl];
    q += p[128 + cl];
  }
  red_s[t] = s; red_q[t] = q;
  __syncthreads();
#pragma unroll
  for (int off = 64; off > 0; off >>= 1) {
    if (t < off) {
      red_s[t] += red_s[t + off];
      red_q[t] += red_q[t + off];
    }
    __syncthreads();
  }
  if (t == 0) {
    s = red_s[0]; q = red_q[0];
    float bc = bl[c];
    s -= (float)(N_PAD - N_NODESC) * bc;
    q -= (float)(N_PAD - N_NODESC) * bc * bc;
    const float invN = 1.0f / (float)N_NODESC;
    float mu = s * invN;
    float var = q * invN - mu * mu;
    float rsq = rsqrtf(var + 1e-5f);
    float sc = gamma[c] * rsq;
    float sh = beta[c] - mu * sc;
    scale[c] = sc;
    shiftv[c] = sh;
    sc16[c] = f2h(sc);
    sh16[c] = f2h(sh);
  }
}

// ---------------------------------------------------------------- mean pooling
__device__ __forceinline__ int lower_bound_g(const int* gid, int n, int g)
{
  int lo = 0, hi = n;
  while (lo < hi) {
    int mid = (lo + hi) >> 1;
    if (gid[mid] < g) lo = mid + 1; else hi = mid;
  }
  return lo;
}

__global__ __launch_bounds__(512) void pool_k(
    const unsigned short* __restrict__ Y16, const int* __restrict__ gid,
    const float* __restrict__ scale, const float* __restrict__ shiftv,
    float* __restrict__ gpool)
{
  __shared__ float red[8 * 256];
  int g = blockIdx.x;
  int lo = lower_bound_g(gid, N_NODESC, g);
  int hi = lower_bound_g(gid, N_NODESC, g + 1);
  int t = threadIdx.x;
  int w = t >> 6, lane = t & 63;
  int col = lane * 4;
  long ybase = (long)(col >> 5) * SLAB + (col & 31);
  float4 sc = *(const float4*)(scale + col);
  float4 sh = *(const float4*)(shiftv + col);
  float a0 = 0.f, a1 = 0.f, a2 = 0.f, a3 = 0.f;
  for (int r = lo + w; r < hi; r += 8) {
    ushort4 u = *(const ushort4*)(Y16 + ybase + (long)r * 32);
    a0 += fmaxf(0.f, h2f(u.x) * sc.x + sh.x);
    a1 += fmaxf(0.f, h2f(u.y) * sc.y + sh.y);
    a2 += fmaxf(0.f, h2f(u.z) * sc.z + sh.z);
    a3 += fmaxf(0.f, h2f(u.w) * sc.w + sh.w);
  }
  *(float4*)&red[w * 256 + col] = make_float4(a0, a1, a2, a3);
  __syncthreads();
  if (t < 256) {
    float s = 0.f;
#pragma unroll
    for (int j = 0; j < 8; ++j) s += red[j * 256 + t];
    int c = hi - lo;
    gpool[g * 256 + t] = s / (float)(c > 0 ? c : 1);
  }
}

// ---------------------------------------------------------------- final proj
__global__ __launch_bounds__(128) void final_k(
    const float* __restrict__ gpool, const float* __restrict__ Wp,
    const float* __restrict__ bp, float* __restrict__ out)
{
  __shared__ float gr[256];
  int g = blockIdx.x, t = threadIdx.x;
  gr[t] = gpool[g * 256 + t];
  gr[t + 128] = gpool[g * 256 + t + 128];
  __syncthreads();
  float acc = bp[t];
#pragma unroll 8
  for (int k = 0; k < 256; ++k) acc += gr[k] * Wp[k * 128 + t];
  out[g * 128 + t] = acc;
}

// ---------------------------------------------------------------- launcher
extern "C" void kernel_launch(void* const* d_in, const int* in_sizes, int n_in,
                              void* d_out, int out_size, void* d_ws, size_t ws_size,
                              hipStream_t stream)
{
  (void)in_sizes; (void)n_in; (void)out_size; (void)ws_size;
  const int* nfeat = (const int*)d_in[0];
  const int* efeat = (const int*)d_in[1];
  const int* src = (const int*)d_in[2];
  const int* dst = (const int*)d_in[3];
  const int* gid = (const int*)d_in[4];
  const float* atom_emb = (const float*)d_in[5];
  const float* edge_emb = (const float*)d_in[6];
  const float* W = (const float*)d_in[7];
  const float* b = (const float*)d_in[8];
  const float* gamma = (const float*)d_in[9];
  const float* beta = (const float*)d_in[10];
  const float* Wp = (const float*)d_in[11];
  const float* bp = (const float*)d_in[12];
  float* out = (float*)d_out;

  char* ws = (char*)d_ws;
  unsigned short* h16 = (unsigned short*)ws; ws += (size_t)N_PAD * 512;
  unsigned short* Y16 = (unsigned short*)ws; ws += (size_t)N_PAD * 512;
  unsigned short* X16 = (unsigned short*)ws; ws += (size_t)N_PAD * 512;
  unsigned short* Wt = (unsigned short*)ws; ws += 5 * 65536 * 2;
  unsigned short* EWt = (unsigned short*)ws; ws += 5 * 256 * 32 * 2;
  unsigned short* cntf = (unsigned short*)ws; ws += (size_t)N_PAD * 32 * 2;
  int* csrc = (int*)ws; ws += 3200000;
  int* ceid = (int*)ws; ws += 3200000;
  int* row_start = (int*)ws; ws += 200064;
  int* degs_i = (int*)ws; ws += 200064;
  int* fill = (int*)ws; ws += 200064;
  int* bsum = (int*)ws; ws += 256;
  int* boff = (int*)ws; ws += 256;
  float* Pp = (float*)ws; ws += MTILES * 2 * 256 * 4;
  float* scale = (float*)ws; ws += 1024;
  float* shiftv = (float*)ws; ws += 1024;
  unsigned short* sc16 = (unsigned short*)ws; ws += 512;
  unsigned short* sh16 = (unsigned short*)ws; ws += 512;
  float* gpool = (float*)ws; ws += 131072;

  hipMemsetAsync(degs_i, 0, 200000, stream);
  hipMemsetAsync(fill, 0, 200000, stream);
  // zero X16 pad rows in each slice slab so GEMM pad output is exactly b[c]
  for (int s = 0; s < 8; ++s)
    hipMemsetAsync(X16 + (size_t)s * SLAB + (size_t)N_NODESC * 32, 0,
                   (size_t)(N_PAD - N_NODESC) * 64, stream);

  wprep_k<<<1280, 256, 0, stream>>>(W, Wt);
  ew_k<<<120, 256, 0, stream>>>(edge_emb, W, EWt);
  atom_encode_k<<<12500, 256, 0, stream>>>(nfeat, atom_emb, h16);
  deg_k<<<3125, 256, 0, stream>>>(dst, degs_i);
  scan_partial_k<<<49, 256, 0, stream>>>(degs_i, bsum);
  scan_sums_k<<<1, 64, 0, stream>>>(bsum, boff);
  scan_final_k<<<49, 256, 0, stream>>>(degs_i, boff, row_start);
  scatter_k<<<25000, 256, 0, stream>>>(src, dst, row_start, fill, csrc, ceid);
  cntf_k<<<196, 256, 0, stream>>>(ceid, row_start, efeat, cntf);

  // layer 0 aggregate: atom-encoded h16, no BN
  aggregate_t<0><<<12504, 256, 0, stream>>>(h16, csrc, row_start,
                                            nullptr, nullptr, X16);
  for (int l = 0; l < 5; ++l) {
    gemm_k<<<dim3(MTILES, 2), 256, 0, stream>>>(X16, Wt + l * 65536, cntf,
                                                EWt + l * 8192, b + l * 256,
                                                Y16, Pp);
    stats_finalize_k<<<256, 128, 0, stream>>>(Pp, b + l * 256, gamma + l * 256,
                                              beta + l * 256, scale, shiftv,
                                              sc16, sh16);
    if (l < 4)
      aggregate_t<1><<<12504, 256, 0, stream>>>(Y16, csrc, row_start,
                                                sc16, sh16, X16);
  }

  pool_k<<<128, 512, 0, stream>>>(Y16, gid, scale, shiftv, gpool);
  final_k<<<128, 128, 0, stream>>>(gpool, Wp, bp, out);
}